// Round 16
// baseline (536.732 us; speedup 1.0000x reference)
//
#include <hip/hip_runtime.h>
#include <hip/hip_bf16.h>

#define DIMC 3072
#define NHEADS 24
#define HD 128
#define SEQ 2560
#define TXTLEN 512
#define IMGLEN 2048

using short8 = __attribute__((ext_vector_type(8))) short;
using f32x4  = __attribute__((ext_vector_type(4))) float;

static __device__ __forceinline__ float bf2f(unsigned short u) {
    unsigned v = ((unsigned)u) << 16;
    return __builtin_bit_cast(float, v);
}
static __device__ __forceinline__ unsigned short f2bf(float f) {
    unsigned u = __builtin_bit_cast(unsigned, f);
    return (unsigned short)((u + 0x7FFFu + ((u >> 16) & 1u)) >> 16);
}
static __device__ __forceinline__ void gload16(const void* g, void* l) {
    __builtin_amdgcn_global_load_lds((const __attribute__((address_space(1))) unsigned int*)g,
                                     (__attribute__((address_space(3))) unsigned int*)l,
                                     16, 0, 0);
}

// ---------------------------------------------------------------------------
// Single grid-stride f32->bf16 cast over all 10 tensors (2 acts + 8 weights).
// Segments (in float8 groups): ctx 196608, x 786432, 8 x weights 1179648.
// ---------------------------------------------------------------------------
struct CastAll { const float* src[10]; unsigned short* dst[10]; };

__global__ __launch_bounds__(256)
void castall(CastAll a, size_t total)
{
    const size_t stride = (size_t)gridDim.x * 256;
    for (size_t g = (size_t)blockIdx.x * 256 + threadIdx.x; g < total; g += stride) {
        int seg; size_t idx;
        if (g < 196608)      { seg = 0; idx = g; }
        else if (g < 983040) { seg = 1; idx = g - 196608; }
        else {
            const size_t wi = g - 983040;
            const int wseg = (int)(wi / 1179648u);
            seg = 2 + wseg;
            idx = wi - (size_t)wseg * 1179648u;
        }
        const float* in = a.src[seg] + idx * 8;
        unsigned short* out = a.dst[seg] + idx * 8;
        const float4 av = *reinterpret_cast<const float4*>(in);
        const float4 bv = *reinterpret_cast<const float4*>(in + 4);
        short8 o;
        o[0] = (short)f2bf(av.x); o[1] = (short)f2bf(av.y);
        o[2] = (short)f2bf(av.z); o[3] = (short)f2bf(av.w);
        o[4] = (short)f2bf(bv.x); o[5] = (short)f2bf(bv.y);
        o[6] = (short)f2bf(bv.z); o[7] = (short)f2bf(bv.w);
        *reinterpret_cast<short8*>(out) = o;
    }
}

// ---------------------------------------------------------------------------
// QKV GEMM: 128x128 tile, BK=32, 3-buffer pipeline staged 2 ahead, counted
// vmcnt(4). LDS bank-swizzle: 16B slot ^= (row>>1)&3, on BOTH the
// pre-swizzled global source (linear gload_lds dest) and the ds_read slot.
// XCD-bijective grid swizzle (1440 blocks, chunk 180).
// ---------------------------------------------------------------------------
struct QkvArgs {
    const unsigned short* A;
    const unsigned short* w0[3];
    const unsigned short* w1[3];
    unsigned short* c[3];
};

__global__ __launch_bounds__(256)
void gemm_qkv(QkvArgs args)
{
    __shared__ unsigned short As[3][128 * 32];
    __shared__ unsigned short Bs[3][128 * 32];

    const int bid = blockIdx.x;
    const int swz = (bid & 7) * 180 + (bid >> 3);
    const int bm = swz % 20;
    int bn = swz / 20;                       // 0..71
    const int which = bn / 24; bn -= which * 24;

    const int rowbase = bm * 128, colbase = bn * 128;
    const unsigned short* __restrict__ A = args.A;
    const unsigned short* __restrict__ W = (rowbase < TXTLEN) ? args.w0[which] : args.w1[which];
    unsigned short* __restrict__ C = args.c[which];

    const int t = threadIdx.x, w = t >> 6, l = t & 63;
    const int lr = l & 15, lk = l >> 4;
    const int wr = (w >> 1) * 64, wc = (w & 1) * 64;

    f32x4 acc[4][4] = {};

    const int ssl = ((l & 3) ^ ((l >> 3) & 3)) * 8;   // pre-swizzled source slot
    const unsigned short* Ag = A + (size_t)(rowbase + w * 32 + (l >> 2)) * DIMC + ssl;
    const unsigned short* Wg = W + (size_t)(colbase + w * 32 + (l >> 2)) * DIMC + ssl;

    auto STAGE = [&](int buf, int k0) {
        gload16(Ag + k0,             &As[buf][w * 1024]);
        gload16(Ag + 16 * DIMC + k0, &As[buf][w * 1024 + 512]);
        gload16(Wg + k0,             &Bs[buf][w * 1024]);
        gload16(Wg + 16 * DIMC + k0, &Bs[buf][w * 1024 + 512]);
    };

    constexpr int NIT = DIMC / 32;   // 96
    STAGE(0, 0);
    STAGE(1, 32);

    const int rsl = (lk ^ ((lr >> 1) & 3)) * 8;   // swizzled ds_read slot
    int buf = 0;
    for (int it = 0; it < NIT; ++it) {
        asm volatile("s_waitcnt vmcnt(4)" ::: "memory");
        __builtin_amdgcn_s_barrier();
        asm volatile("" ::: "memory");

        {
            const int k2 = (it + 2 < NIT) ? (it + 2) : (NIT - 1);
            int b2 = buf + 2; if (b2 >= 3) b2 -= 3;
            STAGE(b2, k2 * 32);
        }

        short8 af[4], bf[4];
#pragma unroll
        for (int m = 0; m < 4; ++m)
            af[m] = *reinterpret_cast<const short8*>(&As[buf][(wr + m * 16 + lr) * 32 + rsl]);
#pragma unroll
        for (int n = 0; n < 4; ++n)
            bf[n] = *reinterpret_cast<const short8*>(&Bs[buf][(wc + n * 16 + lr) * 32 + rsl]);

        __builtin_amdgcn_s_setprio(1);
#pragma unroll
        for (int m = 0; m < 4; ++m)
#pragma unroll
            for (int n = 0; n < 4; ++n)
                acc[m][n] = __builtin_amdgcn_mfma_f32_16x16x32_bf16(af[m], bf[n], acc[m][n], 0, 0, 0);
        __builtin_amdgcn_s_setprio(0);

        buf = (buf + 1 == 3) ? 0 : buf + 1;
    }

#pragma unroll
    for (int m = 0; m < 4; ++m) {
#pragma unroll
        for (int r = 0; r < 4; ++r) {
            const int row = rowbase + wr + m * 16 + lk * 4 + r;
            unsigned short* crow = C + (size_t)row * DIMC + colbase + wc;
#pragma unroll
            for (int n = 0; n < 4; ++n)
                crow[n * 16 + lr] = f2bf(acc[m][n][r]);
        }
    }
}

// ---------------------------------------------------------------------------
// Output projection GEMM (f32 out, txt/img split), same pipeline + swizzle.
// ---------------------------------------------------------------------------
__global__ __launch_bounds__(256)
void gemm_out(const unsigned short* __restrict__ A, const unsigned short* __restrict__ W0,
              const unsigned short* __restrict__ W1, float* __restrict__ Ctxt,
              float* __restrict__ Cimg)
{
    __shared__ unsigned short As[3][128 * 32];
    __shared__ unsigned short Bs[3][128 * 32];

    const int bid = blockIdx.x;
    const int swz = (bid & 7) * 60 + (bid >> 3);
    const int bm = swz % 20;
    const int bn = swz / 20;                  // 0..23

    const int rowbase = bm * 128, colbase = bn * 128;
    const unsigned short* __restrict__ W = (rowbase < TXTLEN) ? W0 : W1;

    const int t = threadIdx.x, w = t >> 6, l = t & 63;
    const int lr = l & 15, lk = l >> 4;
    const int wr = (w >> 1) * 64, wc = (w & 1) * 64;

    f32x4 acc[4][4] = {};

    const int ssl = ((l & 3) ^ ((l >> 3) & 3)) * 8;
    const unsigned short* Ag = A + (size_t)(rowbase + w * 32 + (l >> 2)) * DIMC + ssl;
    const unsigned short* Wg = W + (size_t)(colbase + w * 32 + (l >> 2)) * DIMC + ssl;

    auto STAGE = [&](int buf, int k0) {
        gload16(Ag + k0,             &As[buf][w * 1024]);
        gload16(Ag + 16 * DIMC + k0, &As[buf][w * 1024 + 512]);
        gload16(Wg + k0,             &Bs[buf][w * 1024]);
        gload16(Wg + 16 * DIMC + k0, &Bs[buf][w * 1024 + 512]);
    };

    constexpr int NIT = DIMC / 32;
    STAGE(0, 0);
    STAGE(1, 32);

    const int rsl = (lk ^ ((lr >> 1) & 3)) * 8;
    int buf = 0;
    for (int it = 0; it < NIT; ++it) {
        asm volatile("s_waitcnt vmcnt(4)" ::: "memory");
        __builtin_amdgcn_s_barrier();
        asm volatile("" ::: "memory");

        {
            const int k2 = (it + 2 < NIT) ? (it + 2) : (NIT - 1);
            int b2 = buf + 2; if (b2 >= 3) b2 -= 3;
            STAGE(b2, k2 * 32);
        }

        short8 af[4], bf[4];
#pragma unroll
        for (int m = 0; m < 4; ++m)
            af[m] = *reinterpret_cast<const short8*>(&As[buf][(wr + m * 16 + lr) * 32 + rsl]);
#pragma unroll
        for (int n = 0; n < 4; ++n)
            bf[n] = *reinterpret_cast<const short8*>(&Bs[buf][(wc + n * 16 + lr) * 32 + rsl]);

        __builtin_amdgcn_s_setprio(1);
#pragma unroll
        for (int m = 0; m < 4; ++m)
#pragma unroll
            for (int n = 0; n < 4; ++n)
                acc[m][n] = __builtin_amdgcn_mfma_f32_16x16x32_bf16(af[m], bf[n], acc[m][n], 0, 0, 0);
        __builtin_amdgcn_s_setprio(0);

        buf = (buf + 1 == 3) ? 0 : buf + 1;
    }

    float* Cb; int rloc;
    if (rowbase < TXTLEN) { Cb = Ctxt; rloc = rowbase; }
    else                  { Cb = Cimg; rloc = rowbase - TXTLEN; }
#pragma unroll
    for (int m = 0; m < 4; ++m) {
#pragma unroll
        for (int r = 0; r < 4; ++r) {
            const int row = rloc + wr + m * 16 + lk * 4 + r;
            float* crow = Cb + (size_t)row * DIMC + colbase + wc;
#pragma unroll
            for (int n = 0; n < 4; ++n)
                crow[n * 16 + lr] = acc[m][n][r];
        }
    }
}

// ---------------------------------------------------------------------------
// RMSNorm + RoPE (+ 1/sqrt(HD) folded into Q), bf16 in/out.
// ---------------------------------------------------------------------------
__global__ __launch_bounds__(256)
void normrope(unsigned short* __restrict__ Q, unsigned short* __restrict__ K,
              const float* __restrict__ gq, const float* __restrict__ gk,
              const float* __restrict__ agq, const float* __restrict__ agk,
              const float* __restrict__ rc, const float* __restrict__ rs)
{
    const int wid  = (blockIdx.x << 2) + (threadIdx.x >> 6);
    const int lane = threadIdx.x & 63;
    const int s = wid / NHEADS, h = wid - s * NHEADS;
    const bool img = (s >= TXTLEN);
    const float* gq_ = img ? gq : agq;
    const float* gk_ = img ? gk : agk;

    const size_t base = (size_t)s * DIMC + h * HD + lane * 2;
    const float2 c2  = *reinterpret_cast<const float2*>(rc + (size_t)s * HD + lane * 2);
    const float2 s2  = *reinterpret_cast<const float2*>(rs + (size_t)s * HD + lane * 2);
    const float2 gqv = *reinterpret_cast<const float2*>(gq_ + lane * 2);
    const float2 gkv = *reinterpret_cast<const float2*>(gk_ + lane * 2);

    {
        unsigned pr = *reinterpret_cast<unsigned*>(Q + base);
        float vx = bf2f((unsigned short)(pr & 0xffff));
        float vy = bf2f((unsigned short)(pr >> 16));
        float ss = vx * vx + vy * vy;
#pragma unroll
        for (int off = 1; off < 64; off <<= 1) ss += __shfl_xor(ss, off);
        const float rr = rsqrtf(ss * (1.f / HD) + 1e-6f);
        const float txv = vx * rr * gqv.x, tyv = vy * rr * gqv.y;
        const float qs = 0.08838834764831845f;
        const float ox = (txv * c2.x - tyv * s2.x) * qs;
        const float oy = (tyv * c2.y + txv * s2.y) * qs;
        *reinterpret_cast<unsigned*>(Q + base) = (unsigned)f2bf(ox) | ((unsigned)f2bf(oy) << 16);
    }
    {
        unsigned pr = *reinterpret_cast<unsigned*>(K + base);
        float vx = bf2f((unsigned short)(pr & 0xffff));
        float vy = bf2f((unsigned short)(pr >> 16));
        float ss = vx * vx + vy * vy;
#pragma unroll
        for (int off = 1; off < 64; off <<= 1) ss += __shfl_xor(ss, off);
        const float rr = rsqrtf(ss * (1.f / HD) + 1e-6f);
        const float txv = vx * rr * gkv.x, tyv = vy * rr * gkv.y;
        const float ox = txv * c2.x - tyv * s2.x;
        const float oy = tyv * c2.y + txv * s2.y;
        *reinterpret_cast<unsigned*>(K + base) = (unsigned)f2bf(ox) | ((unsigned)f2bf(oy) << 16);
    }
}

// ---------------------------------------------------------------------------
// V[2560][3072] -> Vt[24][128][2560]
// ---------------------------------------------------------------------------
__global__ __launch_bounds__(256)
void transpose_v(const unsigned short* __restrict__ V, unsigned short* __restrict__ Vt)
{
    __shared__ unsigned short Ts[64][136];
    const int kt = blockIdx.x, h = blockIdx.y;
    const int t = threadIdx.x;
#pragma unroll
    for (int p = 0; p < 4; ++p) {
        const int row = p * 16 + (t >> 4);
        const int col = (t & 15) * 8;
        *reinterpret_cast<short8*>(&Ts[row][col]) =
            *reinterpret_cast<const short8*>(V + (size_t)(kt * 64 + row) * DIMC + h * HD + col);
    }
    __syncthreads();
    const int d = t >> 1, kh = t & 1;
    unsigned short* dst = Vt + (size_t)h * HD * SEQ + (size_t)d * SEQ + kt * 64 + kh * 32;
#pragma unroll
    for (int j4 = 0; j4 < 4; ++j4) {
        short8 o;
#pragma unroll
        for (int j = 0; j < 8; ++j) o[j] = (short)Ts[kh * 32 + j4 * 8 + j][d];
        *reinterpret_cast<short8*>(dst + j4 * 8) = o;
    }
}

// ---------------------------------------------------------------------------
// Flash attention: 128 q-rows x 1 head per block, 8 waves, XCD-swizzled grid.
// K/V double-buffered (XOR-swizzled via pre-swizzled global src).
// T5 setprio + T13 defer-max.
// ---------------------------------------------------------------------------
__global__ __launch_bounds__(512)
void attn_mfma(const unsigned short* __restrict__ Q, const unsigned short* __restrict__ K,
               const unsigned short* __restrict__ Vt, unsigned short* __restrict__ O)
{
    __shared__ unsigned short Ks[2][64 * 128];   // [kv][d], slot^=(kv&7)
    __shared__ unsigned short Vs[2][128 * 64];   // [d][kv], slot^=(d&7)
    __shared__ unsigned short Ps[8][16 * 64];    // per-wave P, swizzled

    const int bid = blockIdx.x;
    const int swz = (bid & 7) * 60 + (bid >> 3);
    const int bq = swz % 20;
    const int h  = swz / 20;

    const int t = threadIdx.x, w = t >> 6, l = t & 63;
    const int lr = l & 15, lk = l >> 4;
    const int q0 = bq * 128 + w * 16;

    short8 qf[4];
#pragma unroll
    for (int kk = 0; kk < 4; ++kk)
        qf[kk] = *reinterpret_cast<const short8*>(
            Q + (size_t)(q0 + lr) * DIMC + h * HD + kk * 32 + lk * 8);

    f32x4 oacc[8] = {};
    float mrow[4] = {-1e30f, -1e30f, -1e30f, -1e30f};
    float lrow[4] = {};

    const unsigned short* Kg[2];
    const unsigned short* Vg[2];
#pragma unroll
    for (int i = 0; i < 2; ++i) {
        const int kr = w * 8 + i * 4 + (l >> 4);
        Kg[i] = K + (size_t)kr * DIMC + h * HD + (((l & 15) ^ (kr & 7)) * 8);
        const int vr = w * 16 + i * 8 + (l >> 3);
        Vg[i] = Vt + (size_t)h * HD * SEQ + (size_t)vr * SEQ + (((l & 7) ^ (vr & 7)) * 8);
    }

    auto STAGE = [&](int buf, int kv0) {
#pragma unroll
        for (int i = 0; i < 2; ++i) {
            gload16(Kg[i] + (size_t)kv0 * DIMC, &Ks[buf][(w * 8 + i * 4) * 128]);
            gload16(Vg[i] + kv0,                &Vs[buf][(w * 16 + i * 8) * 64]);
        }
    };

    STAGE(0, 0);

    constexpr int NT = SEQ / 64;  // 40
    for (int kt = 0; kt < NT; ++kt) {
        const int buf = kt & 1;
        __syncthreads();
        if (kt + 1 < NT) STAGE(buf ^ 1, (kt + 1) * 64);

        // S = Q K^T
        f32x4 sf[4] = {};
        __builtin_amdgcn_s_setprio(1);
#pragma unroll
        for (int nf = 0; nf < 4; ++nf) {
            const int row = nf * 16 + lr;
            const int sw = (row & 7) << 3;
#pragma unroll
            for (int kk = 0; kk < 4; ++kk) {
                short8 bfr = *reinterpret_cast<const short8*>(
                    &Ks[buf][row * 128 + ((kk * 32 + lk * 8) ^ sw)]);
                sf[nf] = __builtin_amdgcn_mfma_f32_16x16x32_bf16(qf[kk], bfr, sf[nf], 0, 0, 0);
            }
        }
        __builtin_amdgcn_s_setprio(0);

        // online softmax with defer-max (T13)
        float mxr[4];
#pragma unroll
        for (int r = 0; r < 4; ++r) {
            float mx = fmaxf(fmaxf(sf[0][r], sf[1][r]), fmaxf(sf[2][r], sf[3][r]));
#pragma unroll
            for (int off = 1; off < 16; off <<= 1) mx = fmaxf(mx, __shfl_xor(mx, off));
            mxr[r] = mx;
        }
        const float need = fmaxf(fmaxf(mxr[0] - mrow[0], mxr[1] - mrow[1]),
                                 fmaxf(mxr[2] - mrow[2], mxr[3] - mrow[3]));
        if (!__all(need <= 8.0f)) {
#pragma unroll
            for (int r = 0; r < 4; ++r) {
                const float mn = fmaxf(mrow[r], mxr[r]);
                const float alpha = __expf(mrow[r] - mn);
                mrow[r] = mn;
                lrow[r] *= alpha;
#pragma unroll
                for (int nf = 0; nf < 8; ++nf) oacc[nf][r] *= alpha;
            }
        }
#pragma unroll
        for (int r = 0; r < 4; ++r) {
            float ps = 0.f;
#pragma unroll
            for (int nf = 0; nf < 4; ++nf) {
                const float p = __expf(sf[nf][r] - mrow[r]);
                sf[nf][r] = p;
                ps += p;
            }
#pragma unroll
            for (int off = 1; off < 16; off <<= 1) ps += __shfl_xor(ps, off);
            lrow[r] += ps;
        }

        // P -> per-wave LDS (swizzled); same-wave producer/consumer
#pragma unroll
        for (int r = 0; r < 4; ++r) {
            const int prow = lk * 4 + r;
            const int sw = (prow & 7) << 3;
#pragma unroll
            for (int nf = 0; nf < 4; ++nf) {
                const int col = nf * 16 + lr;
                Ps[w][prow * 64 + (col ^ sw)] = f2bf(sf[nf][r]);
            }
        }

        // O += P V
        __builtin_amdgcn_s_setprio(1);
#pragma unroll
        for (int ks = 0; ks < 2; ++ks) {
            short8 pa = *reinterpret_cast<const short8*>(
                &Ps[w][lr * 64 + ((ks * 32 + lk * 8) ^ ((lr & 7) << 3))]);
#pragma unroll
            for (int nf = 0; nf < 8; ++nf) {
                const int vrow = nf * 16 + lr;
                short8 vf = *reinterpret_cast<const short8*>(
                    &Vs[buf][vrow * 64 + ((ks * 32 + lk * 8) ^ ((vrow & 7) << 3))]);
                oacc[nf] = __builtin_amdgcn_mfma_f32_16x16x32_bf16(pa, vf, oacc[nf], 0, 0, 0);
            }
        }
        __builtin_amdgcn_s_setprio(0);
    }

    float inv[4];
#pragma unroll
    for (int r = 0; r < 4; ++r) inv[r] = 1.f / lrow[r];
#pragma unroll
    for (int nf = 0; nf < 8; ++nf)
#pragma unroll
        for (int r = 0; r < 4; ++r)
            O[(size_t)(q0 + lk * 4 + r) * DIMC + h * HD + nf * 16 + lr] = f2bf(oacc[nf][r] * inv[r]);
}

// ---------------------------------------------------------------------------
extern "C" void kernel_launch(void* const* d_in, const int* in_sizes, int n_in,
                              void* d_out, int out_size, void* d_ws, size_t ws_size,
                              hipStream_t stream)
{
    const float* x    = (const float*)d_in[0];
    const float* ctx  = (const float*)d_in[1];
    const float* rc   = (const float*)d_in[2];
    const float* rs   = (const float*)d_in[3];
    const float* wq   = (const float*)d_in[4];
    const float* wk   = (const float*)d_in[5];
    const float* wv   = (const float*)d_in[6];
    const float* gq   = (const float*)d_in[7];
    const float* gk   = (const float*)d_in[8];
    const float* wo   = (const float*)d_in[9];
    const float* awq  = (const float*)d_in[10];
    const float* awk  = (const float*)d_in[11];
    const float* awv  = (const float*)d_in[12];
    const float* agq  = (const float*)d_in[13];
    const float* agk  = (const float*)d_in[14];
    const float* awo  = (const float*)d_in[15];

    unsigned short* wsp = (unsigned short*)d_ws;
    const size_t SZ  = (size_t)SEQ * DIMC;
    const size_t WSZ = (size_t)DIMC * DIMC;
    unsigned short* XC  = wsp;
    unsigned short* Qb  = XC + SZ;
    unsigned short* Kb  = Qb + SZ;
    unsigned short* Vb  = Kb + SZ;
    unsigned short* Vtb = Vb + SZ;
    unsigned short* Ob  = Vtb + SZ;
    unsigned short* Wc  = Ob + SZ;  // 8 weights: awq, wq, awk, wk, awv, wv, awo, wo

    {
        CastAll ca;
        ca.src[0] = ctx;  ca.dst[0] = XC;
        ca.src[1] = x;    ca.dst[1] = XC + (size_t)TXTLEN * DIMC;
        const float* wsrc[8] = {awq, wq, awk, wk, awv, wv, awo, wo};
        for (int i = 0; i < 8; ++i) { ca.src[2 + i] = wsrc[i]; ca.dst[2 + i] = Wc + (size_t)i * WSZ; }
        const size_t total = 983040u + 8u * 1179648u;   // float8 groups
        castall<<<dim3(2048), dim3(256), 0, stream>>>(ca, total);
    }

    QkvArgs qa;
    qa.A = XC;
    qa.w0[0] = Wc + 0 * WSZ; qa.w1[0] = Wc + 1 * WSZ; qa.c[0] = Qb;
    qa.w0[1] = Wc + 2 * WSZ; qa.w1[1] = Wc + 3 * WSZ; qa.c[1] = Kb;
    qa.w0[2] = Wc + 4 * WSZ; qa.w1[2] = Wc + 5 * WSZ; qa.c[2] = Vb;
    gemm_qkv<<<dim3(1440), dim3(256), 0, stream>>>(qa);

    normrope<<<dim3(SEQ * NHEADS / 4), dim3(256), 0, stream>>>(Qb, Kb, gq, gk, agq, agk, rc, rs);

    transpose_v<<<dim3(SEQ / 64, NHEADS), dim3(256), 0, stream>>>(Vb, Vtb);

    attn_mfma<<<dim3(480), dim3(512), 0, stream>>>(Qb, Kb, Vtb, Ob);

    float* out = (float*)d_out;
    gemm_out<<<dim3(480), dim3(256), 0, stream>>>(
        Ob, Wc + 6 * WSZ, Wc + 7 * WSZ, out + (size_t)IMGLEN * DIMC, out);
}

// Round 17
// 533.569 us; speedup vs baseline: 1.0059x; 1.0059x over previous
//
#include <hip/hip_runtime.h>
#include <hip/hip_bf16.h>

#define DIMC 3072
#define NHEADS 24
#define HD 128
#define SEQ 2560
#define TXTLEN 512
#define IMGLEN 2048

using short8 = __attribute__((ext_vector_type(8))) short;
using f32x4  = __attribute__((ext_vector_type(4))) float;

static __device__ __forceinline__ float bf2f(unsigned short u) {
    unsigned v = ((unsigned)u) << 16;
    return __builtin_bit_cast(float, v);
}
static __device__ __forceinline__ unsigned short f2bf(float f) {
    unsigned u = __builtin_bit_cast(unsigned, f);
    return (unsigned short)((u + 0x7FFFu + ((u >> 16) & 1u)) >> 16);
}
static __device__ __forceinline__ void gload16(const void* g, void* l) {
    __builtin_amdgcn_global_load_lds((const __attribute__((address_space(1))) unsigned int*)g,
                                     (__attribute__((address_space(3))) unsigned int*)l,
                                     16, 0, 0);
}

// ---------------------------------------------------------------------------
// f32 -> bf16 casts: activations (2 sources, one dispatch) and 8 weights.
// ---------------------------------------------------------------------------
struct C2 { const float* src[2]; size_t n8[2]; unsigned short* dst[2]; };
__global__ __launch_bounds__(256)
void castk2(C2 a)
{
    const int which = blockIdx.y;
    const size_t i = (size_t)blockIdx.x * 256 + threadIdx.x;
    if (i >= a.n8[which]) return;
    const float* in = a.src[which];
    unsigned short* out = a.dst[which];
    const float4 av = *reinterpret_cast<const float4*>(in + i * 8);
    const float4 bv = *reinterpret_cast<const float4*>(in + i * 8 + 4);
    short8 o;
    o[0] = (short)f2bf(av.x); o[1] = (short)f2bf(av.y);
    o[2] = (short)f2bf(av.z); o[3] = (short)f2bf(av.w);
    o[4] = (short)f2bf(bv.x); o[5] = (short)f2bf(bv.y);
    o[6] = (short)f2bf(bv.z); o[7] = (short)f2bf(bv.w);
    *reinterpret_cast<short8*>(out + i * 8) = o;
}

struct W8 { const float* src[8]; };
__global__ __launch_bounds__(256)
void castw(W8 a, unsigned short* __restrict__ dstbase, int n8, size_t wsz)
{
    const int i = blockIdx.x * 256 + threadIdx.x;
    if (i >= n8) return;
    const float* in = a.src[blockIdx.y];
    unsigned short* out = dstbase + (size_t)blockIdx.y * wsz;
    const float4 av = *reinterpret_cast<const float4*>(in + (size_t)i * 8);
    const float4 bv = *reinterpret_cast<const float4*>(in + (size_t)i * 8 + 4);
    short8 o;
    o[0] = (short)f2bf(av.x); o[1] = (short)f2bf(av.y);
    o[2] = (short)f2bf(av.z); o[3] = (short)f2bf(av.w);
    o[4] = (short)f2bf(bv.x); o[5] = (short)f2bf(bv.y);
    o[6] = (short)f2bf(bv.z); o[7] = (short)f2bf(bv.w);
    *reinterpret_cast<short8*>(out + (size_t)i * 8) = o;
}

// ---------------------------------------------------------------------------
// QKV GEMM: 128x128 tile, BK=32, 3-buffer pipeline staged 2 ahead, counted
// vmcnt(4). LDS bank-swizzle: 16B slot ^= (row>>1)&3, on BOTH the
// pre-swizzled global source (linear gload_lds dest) and the ds_read slot.
// XCD-bijective grid swizzle (1440 blocks, chunk 180).
// ---------------------------------------------------------------------------
struct QkvArgs {
    const unsigned short* A;
    const unsigned short* w0[3];
    const unsigned short* w1[3];
    unsigned short* c[3];
};

__global__ __launch_bounds__(256)
void gemm_qkv(QkvArgs args)
{
    __shared__ unsigned short As[3][128 * 32];
    __shared__ unsigned short Bs[3][128 * 32];

    const int bid = blockIdx.x;
    const int swz = (bid & 7) * 180 + (bid >> 3);
    const int bm = swz % 20;
    int bn = swz / 20;                       // 0..71
    const int which = bn / 24; bn -= which * 24;

    const int rowbase = bm * 128, colbase = bn * 128;
    const unsigned short* __restrict__ A = args.A;
    const unsigned short* __restrict__ W = (rowbase < TXTLEN) ? args.w0[which] : args.w1[which];
    unsigned short* __restrict__ C = args.c[which];

    const int t = threadIdx.x, w = t >> 6, l = t & 63;
    const int lr = l & 15, lk = l >> 4;
    const int wr = (w >> 1) * 64, wc = (w & 1) * 64;

    f32x4 acc[4][4] = {};

    const int ssl = ((l & 3) ^ ((l >> 3) & 3)) * 8;   // pre-swizzled source slot
    const unsigned short* Ag = A + (size_t)(rowbase + w * 32 + (l >> 2)) * DIMC + ssl;
    const unsigned short* Wg = W + (size_t)(colbase + w * 32 + (l >> 2)) * DIMC + ssl;

    auto STAGE = [&](int buf, int k0) {
        gload16(Ag + k0,             &As[buf][w * 1024]);
        gload16(Ag + 16 * DIMC + k0, &As[buf][w * 1024 + 512]);
        gload16(Wg + k0,             &Bs[buf][w * 1024]);
        gload16(Wg + 16 * DIMC + k0, &Bs[buf][w * 1024 + 512]);
    };

    constexpr int NIT = DIMC / 32;   // 96
    STAGE(0, 0);
    STAGE(1, 32);

    const int rsl = (lk ^ ((lr >> 1) & 3)) * 8;   // swizzled ds_read slot
    int buf = 0;
    for (int it = 0; it < NIT; ++it) {
        asm volatile("s_waitcnt vmcnt(4)" ::: "memory");
        __builtin_amdgcn_s_barrier();
        asm volatile("" ::: "memory");

        {
            const int k2 = (it + 2 < NIT) ? (it + 2) : (NIT - 1);
            int b2 = buf + 2; if (b2 >= 3) b2 -= 3;
            STAGE(b2, k2 * 32);
        }

        short8 af[4], bf[4];
#pragma unroll
        for (int m = 0; m < 4; ++m)
            af[m] = *reinterpret_cast<const short8*>(&As[buf][(wr + m * 16 + lr) * 32 + rsl]);
#pragma unroll
        for (int n = 0; n < 4; ++n)
            bf[n] = *reinterpret_cast<const short8*>(&Bs[buf][(wc + n * 16 + lr) * 32 + rsl]);

        __builtin_amdgcn_s_setprio(1);
#pragma unroll
        for (int m = 0; m < 4; ++m)
#pragma unroll
            for (int n = 0; n < 4; ++n)
                acc[m][n] = __builtin_amdgcn_mfma_f32_16x16x32_bf16(af[m], bf[n], acc[m][n], 0, 0, 0);
        __builtin_amdgcn_s_setprio(0);

        buf = (buf + 1 == 3) ? 0 : buf + 1;
    }

#pragma unroll
    for (int m = 0; m < 4; ++m) {
#pragma unroll
        for (int r = 0; r < 4; ++r) {
            const int row = rowbase + wr + m * 16 + lk * 4 + r;
            unsigned short* crow = C + (size_t)row * DIMC + colbase + wc;
#pragma unroll
            for (int n = 0; n < 4; ++n)
                crow[n * 16 + lr] = f2bf(acc[m][n][r]);
        }
    }
}

// ---------------------------------------------------------------------------
// Output projection GEMM (f32 out, txt/img split), same pipeline + swizzle.
// ---------------------------------------------------------------------------
__global__ __launch_bounds__(256)
void gemm_out(const unsigned short* __restrict__ A, const unsigned short* __restrict__ W0,
              const unsigned short* __restrict__ W1, float* __restrict__ Ctxt,
              float* __restrict__ Cimg)
{
    __shared__ unsigned short As[3][128 * 32];
    __shared__ unsigned short Bs[3][128 * 32];

    const int bid = blockIdx.x;
    const int swz = (bid & 7) * 60 + (bid >> 3);
    const int bm = swz % 20;
    const int bn = swz / 20;                  // 0..23

    const int rowbase = bm * 128, colbase = bn * 128;
    const unsigned short* __restrict__ W = (rowbase < TXTLEN) ? W0 : W1;

    const int t = threadIdx.x, w = t >> 6, l = t & 63;
    const int lr = l & 15, lk = l >> 4;
    const int wr = (w >> 1) * 64, wc = (w & 1) * 64;

    f32x4 acc[4][4] = {};

    const int ssl = ((l & 3) ^ ((l >> 3) & 3)) * 8;
    const unsigned short* Ag = A + (size_t)(rowbase + w * 32 + (l >> 2)) * DIMC + ssl;
    const unsigned short* Wg = W + (size_t)(colbase + w * 32 + (l >> 2)) * DIMC + ssl;

    auto STAGE = [&](int buf, int k0) {
        gload16(Ag + k0,             &As[buf][w * 1024]);
        gload16(Ag + 16 * DIMC + k0, &As[buf][w * 1024 + 512]);
        gload16(Wg + k0,             &Bs[buf][w * 1024]);
        gload16(Wg + 16 * DIMC + k0, &Bs[buf][w * 1024 + 512]);
    };

    constexpr int NIT = DIMC / 32;
    STAGE(0, 0);
    STAGE(1, 32);

    const int rsl = (lk ^ ((lr >> 1) & 3)) * 8;
    int buf = 0;
    for (int it = 0; it < NIT; ++it) {
        asm volatile("s_waitcnt vmcnt(4)" ::: "memory");
        __builtin_amdgcn_s_barrier();
        asm volatile("" ::: "memory");

        {
            const int k2 = (it + 2 < NIT) ? (it + 2) : (NIT - 1);
            int b2 = buf + 2; if (b2 >= 3) b2 -= 3;
            STAGE(b2, k2 * 32);
        }

        short8 af[4], bf[4];
#pragma unroll
        for (int m = 0; m < 4; ++m)
            af[m] = *reinterpret_cast<const short8*>(&As[buf][(wr + m * 16 + lr) * 32 + rsl]);
#pragma unroll
        for (int n = 0; n < 4; ++n)
            bf[n] = *reinterpret_cast<const short8*>(&Bs[buf][(wc + n * 16 + lr) * 32 + rsl]);

        __builtin_amdgcn_s_setprio(1);
#pragma unroll
        for (int m = 0; m < 4; ++m)
#pragma unroll
            for (int n = 0; n < 4; ++n)
                acc[m][n] = __builtin_amdgcn_mfma_f32_16x16x32_bf16(af[m], bf[n], acc[m][n], 0, 0, 0);
        __builtin_amdgcn_s_setprio(0);

        buf = (buf + 1 == 3) ? 0 : buf + 1;
    }

    float* Cb; int rloc;
    if (rowbase < TXTLEN) { Cb = Ctxt; rloc = rowbase; }
    else                  { Cb = Cimg; rloc = rowbase - TXTLEN; }
#pragma unroll
    for (int m = 0; m < 4; ++m) {
#pragma unroll
        for (int r = 0; r < 4; ++r) {
            const int row = rloc + wr + m * 16 + lk * 4 + r;
            float* crow = Cb + (size_t)row * DIMC + colbase + wc;
#pragma unroll
            for (int n = 0; n < 4; ++n)
                crow[n * 16 + lr] = acc[m][n][r];
        }
    }
}

// ---------------------------------------------------------------------------
// RMSNorm + RoPE (+ 1/sqrt(HD) folded into Q), bf16 in/out.
// ---------------------------------------------------------------------------
__global__ __launch_bounds__(256)
void normrope(unsigned short* __restrict__ Q, unsigned short* __restrict__ K,
              const float* __restrict__ gq, const float* __restrict__ gk,
              const float* __restrict__ agq, const float* __restrict__ agk,
              const float* __restrict__ rc, const float* __restrict__ rs)
{
    const int wid  = (blockIdx.x << 2) + (threadIdx.x >> 6);
    const int lane = threadIdx.x & 63;
    const int s = wid / NHEADS, h = wid - s * NHEADS;
    const bool img = (s >= TXTLEN);
    const float* gq_ = img ? gq : agq;
    const float* gk_ = img ? gk : agk;

    const size_t base = (size_t)s * DIMC + h * HD + lane * 2;
    const float2 c2  = *reinterpret_cast<const float2*>(rc + (size_t)s * HD + lane * 2);
    const float2 s2  = *reinterpret_cast<const float2*>(rs + (size_t)s * HD + lane * 2);
    const float2 gqv = *reinterpret_cast<const float2*>(gq_ + lane * 2);
    const float2 gkv = *reinterpret_cast<const float2*>(gk_ + lane * 2);

    {
        unsigned pr = *reinterpret_cast<unsigned*>(Q + base);
        float vx = bf2f((unsigned short)(pr & 0xffff));
        float vy = bf2f((unsigned short)(pr >> 16));
        float ss = vx * vx + vy * vy;
#pragma unroll
        for (int off = 1; off < 64; off <<= 1) ss += __shfl_xor(ss, off);
        const float rr = rsqrtf(ss * (1.f / HD) + 1e-6f);
        const float txv = vx * rr * gqv.x, tyv = vy * rr * gqv.y;
        const float qs = 0.08838834764831845f;
        const float ox = (txv * c2.x - tyv * s2.x) * qs;
        const float oy = (tyv * c2.y + txv * s2.y) * qs;
        *reinterpret_cast<unsigned*>(Q + base) = (unsigned)f2bf(ox) | ((unsigned)f2bf(oy) << 16);
    }
    {
        unsigned pr = *reinterpret_cast<unsigned*>(K + base);
        float vx = bf2f((unsigned short)(pr & 0xffff));
        float vy = bf2f((unsigned short)(pr >> 16));
        float ss = vx * vx + vy * vy;
#pragma unroll
        for (int off = 1; off < 64; off <<= 1) ss += __shfl_xor(ss, off);
        const float rr = rsqrtf(ss * (1.f / HD) + 1e-6f);
        const float txv = vx * rr * gkv.x, tyv = vy * rr * gkv.y;
        const float ox = txv * c2.x - tyv * s2.x;
        const float oy = tyv * c2.y + txv * s2.y;
        *reinterpret_cast<unsigned*>(K + base) = (unsigned)f2bf(ox) | ((unsigned)f2bf(oy) << 16);
    }
}

// ---------------------------------------------------------------------------
// V[2560][3072] -> Vt[24][128][2560]
// ---------------------------------------------------------------------------
__global__ __launch_bounds__(256)
void transpose_v(const unsigned short* __restrict__ V, unsigned short* __restrict__ Vt)
{
    __shared__ unsigned short Ts[64][136];
    const int kt = blockIdx.x, h = blockIdx.y;
    const int t = threadIdx.x;
#pragma unroll
    for (int p = 0; p < 4; ++p) {
        const int row = p * 16 + (t >> 4);
        const int col = (t & 15) * 8;
        *reinterpret_cast<short8*>(&Ts[row][col]) =
            *reinterpret_cast<const short8*>(V + (size_t)(kt * 64 + row) * DIMC + h * HD + col);
    }
    __syncthreads();
    const int d = t >> 1, kh = t & 1;
    unsigned short* dst = Vt + (size_t)h * HD * SEQ + (size_t)d * SEQ + kt * 64 + kh * 32;
#pragma unroll
    for (int j4 = 0; j4 < 4; ++j4) {
        short8 o;
#pragma unroll
        for (int j = 0; j < 8; ++j) o[j] = (short)Ts[kh * 32 + j4 * 8 + j][d];
        *reinterpret_cast<short8*>(dst + j4 * 8) = o;
    }
}

// ---------------------------------------------------------------------------
// Flash attention: 128 q-rows x 1 head per block, 8 waves, XCD-swizzled grid.
// K/V double-buffered (XOR-swizzled via pre-swizzled global src).
// T5 setprio + T13 defer-max.
// ---------------------------------------------------------------------------
__global__ __launch_bounds__(512)
void attn_mfma(const unsigned short* __restrict__ Q, const unsigned short* __restrict__ K,
               const unsigned short* __restrict__ Vt, unsigned short* __restrict__ O)
{
    __shared__ unsigned short Ks[2][64 * 128];   // [kv][d], slot^=(kv&7)
    __shared__ unsigned short Vs[2][128 * 64];   // [d][kv], slot^=(d&7)
    __shared__ unsigned short Ps[8][16 * 64];    // per-wave P, swizzled

    const int bid = blockIdx.x;
    const int swz = (bid & 7) * 60 + (bid >> 3);
    const int bq = swz % 20;
    const int h  = swz / 20;

    const int t = threadIdx.x, w = t >> 6, l = t & 63;
    const int lr = l & 15, lk = l >> 4;
    const int q0 = bq * 128 + w * 16;

    short8 qf[4];
#pragma unroll
    for (int kk = 0; kk < 4; ++kk)
        qf[kk] = *reinterpret_cast<const short8*>(
            Q + (size_t)(q0 + lr) * DIMC + h * HD + kk * 32 + lk * 8);

    f32x4 oacc[8] = {};
    float mrow[4] = {-1e30f, -1e30f, -1e30f, -1e30f};
    float lrow[4] = {};

    const unsigned short* Kg[2];
    const unsigned short* Vg[2];
#pragma unroll
    for (int i = 0; i < 2; ++i) {
        const int kr = w * 8 + i * 4 + (l >> 4);
        Kg[i] = K + (size_t)kr * DIMC + h * HD + (((l & 15) ^ (kr & 7)) * 8);
        const int vr = w * 16 + i * 8 + (l >> 3);
        Vg[i] = Vt + (size_t)h * HD * SEQ + (size_t)vr * SEQ + (((l & 7) ^ (vr & 7)) * 8);
    }

    auto STAGE = [&](int buf, int kv0) {
#pragma unroll
        for (int i = 0; i < 2; ++i) {
            gload16(Kg[i] + (size_t)kv0 * DIMC, &Ks[buf][(w * 8 + i * 4) * 128]);
            gload16(Vg[i] + kv0,                &Vs[buf][(w * 16 + i * 8) * 64]);
        }
    };

    STAGE(0, 0);

    constexpr int NT = SEQ / 64;  // 40
    for (int kt = 0; kt < NT; ++kt) {
        const int buf = kt & 1;
        __syncthreads();
        if (kt + 1 < NT) STAGE(buf ^ 1, (kt + 1) * 64);

        // S = Q K^T
        f32x4 sf[4] = {};
        __builtin_amdgcn_s_setprio(1);
#pragma unroll
        for (int nf = 0; nf < 4; ++nf) {
            const int row = nf * 16 + lr;
            const int sw = (row & 7) << 3;
#pragma unroll
            for (int kk = 0; kk < 4; ++kk) {
                short8 bfr = *reinterpret_cast<const short8*>(
                    &Ks[buf][row * 128 + ((kk * 32 + lk * 8) ^ sw)]);
                sf[nf] = __builtin_amdgcn_mfma_f32_16x16x32_bf16(qf[kk], bfr, sf[nf], 0, 0, 0);
            }
        }
        __builtin_amdgcn_s_setprio(0);

        // online softmax with defer-max (T13)
        float mxr[4];
#pragma unroll
        for (int r = 0; r < 4; ++r) {
            float mx = fmaxf(fmaxf(sf[0][r], sf[1][r]), fmaxf(sf[2][r], sf[3][r]));
#pragma unroll
            for (int off = 1; off < 16; off <<= 1) mx = fmaxf(mx, __shfl_xor(mx, off));
            mxr[r] = mx;
        }
        const float need = fmaxf(fmaxf(mxr[0] - mrow[0], mxr[1] - mrow[1]),
                                 fmaxf(mxr[2] - mrow[2], mxr[3] - mrow[3]));
        if (!__all(need <= 8.0f)) {
#pragma unroll
            for (int r = 0; r < 4; ++r) {
                const float mn = fmaxf(mrow[r], mxr[r]);
                const float alpha = __expf(mrow[r] - mn);
                mrow[r] = mn;
                lrow[r] *= alpha;
#pragma unroll
                for (int nf = 0; nf < 8; ++nf) oacc[nf][r] *= alpha;
            }
        }
#pragma unroll
        for (int r = 0; r < 4; ++r) {
            float ps = 0.f;
#pragma unroll
            for (int nf = 0; nf < 4; ++nf) {
                const float p = __expf(sf[nf][r] - mrow[r]);
                sf[nf][r] = p;
                ps += p;
            }
#pragma unroll
            for (int off = 1; off < 16; off <<= 1) ps += __shfl_xor(ps, off);
            lrow[r] += ps;
        }

        // P -> per-wave LDS (swizzled); same-wave producer/consumer
#pragma unroll
        for (int r = 0; r < 4; ++r) {
            const int prow = lk * 4 + r;
            const int sw = (prow & 7) << 3;
#pragma unroll
            for (int nf = 0; nf < 4; ++nf) {
                const int col = nf * 16 + lr;
                Ps[w][prow * 64 + (col ^ sw)] = f2bf(sf[nf][r]);
            }
        }

        // O += P V
        __builtin_amdgcn_s_setprio(1);
#pragma unroll
        for (int ks = 0; ks < 2; ++ks) {
            short8 pa = *reinterpret_cast<const short8*>(
                &Ps[w][lr * 64 + ((ks * 32 + lk * 8) ^ ((lr & 7) << 3))]);
#pragma unroll
            for (int nf = 0; nf < 8; ++nf) {
                const int vrow = nf * 16 + lr;
                short8 vf = *reinterpret_cast<const short8*>(
                    &Vs[buf][vrow * 64 + ((ks * 32 + lk * 8) ^ ((vrow & 7) << 3))]);
                oacc[nf] = __builtin_amdgcn_mfma_f32_16x16x32_bf16(pa, vf, oacc[nf], 0, 0, 0);
            }
        }
        __builtin_amdgcn_s_setprio(0);
    }

    float inv[4];
#pragma unroll
    for (int r = 0; r < 4; ++r) inv[r] = 1.f / lrow[r];
#pragma unroll
    for (int nf = 0; nf < 8; ++nf)
#pragma unroll
        for (int r = 0; r < 4; ++r)
            O[(size_t)(q0 + lk * 4 + r) * DIMC + h * HD + nf * 16 + lr] = f2bf(oacc[nf][r] * inv[r]);
}

// ---------------------------------------------------------------------------
extern "C" void kernel_launch(void* const* d_in, const int* in_sizes, int n_in,
                              void* d_out, int out_size, void* d_ws, size_t ws_size,
                              hipStream_t stream)
{
    const float* x    = (const float*)d_in[0];
    const float* ctx  = (const float*)d_in[1];
    const float* rc   = (const float*)d_in[2];
    const float* rs   = (const float*)d_in[3];
    const float* wq   = (const float*)d_in[4];
    const float* wk   = (const float*)d_in[5];
    const float* wv   = (const float*)d_in[6];
    const float* gq   = (const float*)d_in[7];
    const float* gk   = (const float*)d_in[8];
    const float* wo   = (const float*)d_in[9];
    const float* awq  = (const float*)d_in[10];
    const float* awk  = (const float*)d_in[11];
    const float* awv  = (const float*)d_in[12];
    const float* agq  = (const float*)d_in[13];
    const float* agk  = (const float*)d_in[14];
    const float* awo  = (const float*)d_in[15];

    unsigned short* wsp = (unsigned short*)d_ws;
    const size_t SZ  = (size_t)SEQ * DIMC;
    const size_t WSZ = (size_t)DIMC * DIMC;
    unsigned short* XC  = wsp;
    unsigned short* Qb  = XC + SZ;
    unsigned short* Kb  = Qb + SZ;
    unsigned short* Vb  = Kb + SZ;
    unsigned short* Vtb = Vb + SZ;
    unsigned short* Ob  = Vtb + SZ;
    unsigned short* Wc  = Ob + SZ;  // 8 weights: awq, wq, awk, wk, awv, wv, awo, wo

    {
        C2 c2a;
        c2a.src[0] = ctx; c2a.n8[0] = (size_t)TXTLEN * DIMC / 8; c2a.dst[0] = XC;
        c2a.src[1] = x;   c2a.n8[1] = (size_t)IMGLEN * DIMC / 8; c2a.dst[1] = XC + (size_t)TXTLEN * DIMC;
        const int maxb = (int)((c2a.n8[1] + 255) / 256);
        castk2<<<dim3(maxb, 2), dim3(256), 0, stream>>>(c2a);
    }
    {
        W8 w8;
        w8.src[0] = awq; w8.src[1] = wq; w8.src[2] = awk; w8.src[3] = wk;
        w8.src[4] = awv; w8.src[5] = wv; w8.src[6] = awo; w8.src[7] = wo;
        const int n8 = (int)(WSZ / 8);
        castw<<<dim3((n8 + 255) / 256, 8), dim3(256), 0, stream>>>(w8, Wc, n8, WSZ);
    }

    QkvArgs qa;
    qa.A = XC;
    qa.w0[0] = Wc + 0 * WSZ; qa.w1[0] = Wc + 1 * WSZ; qa.c[0] = Qb;
    qa.w0[1] = Wc + 2 * WSZ; qa.w1[1] = Wc + 3 * WSZ; qa.c[1] = Kb;
    qa.w0[2] = Wc + 4 * WSZ; qa.w1[2] = Wc + 5 * WSZ; qa.c[2] = Vb;
    gemm_qkv<<<dim3(1440), dim3(256), 0, stream>>>(qa);

    normrope<<<dim3(SEQ * NHEADS / 4), dim3(256), 0, stream>>>(Qb, Kb, gq, gk, agq, agk, rc, rs);

    transpose_v<<<dim3(SEQ / 64, NHEADS), dim3(256), 0, stream>>>(Vb, Vtb);

    attn_mfma<<<dim3(480), dim3(512), 0, stream>>>(Qb, Kb, Vtb, Ob);

    float* out = (float*)d_out;
    gemm_out<<<dim3(480), dim3(256), 0, stream>>>(
        Ob, Wc + 6 * WSZ, Wc + 7 * WSZ, out + (size_t)IMGLEN * DIMC, out);
}

// Round 18
// 531.721 us; speedup vs baseline: 1.0094x; 1.0035x over previous
//
#include <hip/hip_runtime.h>
#include <hip/hip_bf16.h>

#define DIMC 3072
#define NHEADS 24
#define HD 128
#define SEQ 2560
#define TXTLEN 512
#define IMGLEN 2048

using short8 = __attribute__((ext_vector_type(8))) short;
using f32x4  = __attribute__((ext_vector_type(4))) float;

static __device__ __forceinline__ float bf2f(unsigned short u) {
    unsigned v = ((unsigned)u) << 16;
    return __builtin_bit_cast(float, v);
}
static __device__ __forceinline__ unsigned short f2bf(float f) {
    unsigned u = __builtin_bit_cast(unsigned, f);
    return (unsigned short)((u + 0x7FFFu + ((u >> 16) & 1u)) >> 16);
}
static __device__ __forceinline__ void gload16(const void* g, void* l) {
    __builtin_amdgcn_global_load_lds((const __attribute__((address_space(1))) unsigned int*)g,
                                     (__attribute__((address_space(3))) unsigned int*)l,
                                     16, 0, 0);
}

// ---------------------------------------------------------------------------
// f32 -> bf16 casts: activations (2 sources, one dispatch) and 8 weights.
// ---------------------------------------------------------------------------
struct C2 { const float* src[2]; size_t n8[2]; unsigned short* dst[2]; };
__global__ __launch_bounds__(256)
void castk2(C2 a)
{
    const int which = blockIdx.y;
    const size_t i = (size_t)blockIdx.x * 256 + threadIdx.x;
    if (i >= a.n8[which]) return;
    const float* in = a.src[which];
    unsigned short* out = a.dst[which];
    const float4 av = *reinterpret_cast<const float4*>(in + i * 8);
    const float4 bv = *reinterpret_cast<const float4*>(in + i * 8 + 4);
    short8 o;
    o[0] = (short)f2bf(av.x); o[1] = (short)f2bf(av.y);
    o[2] = (short)f2bf(av.z); o[3] = (short)f2bf(av.w);
    o[4] = (short)f2bf(bv.x); o[5] = (short)f2bf(bv.y);
    o[6] = (short)f2bf(bv.z); o[7] = (short)f2bf(bv.w);
    *reinterpret_cast<short8*>(out + i * 8) = o;
}

struct W8 { const float* src[8]; };
__global__ __launch_bounds__(256)
void castw(W8 a, unsigned short* __restrict__ dstbase, int n8, size_t wsz)
{
    const int i = blockIdx.x * 256 + threadIdx.x;
    if (i >= n8) return;
    const float* in = a.src[blockIdx.y];
    unsigned short* out = dstbase + (size_t)blockIdx.y * wsz;
    const float4 av = *reinterpret_cast<const float4*>(in + (size_t)i * 8);
    const float4 bv = *reinterpret_cast<const float4*>(in + (size_t)i * 8 + 4);
    short8 o;
    o[0] = (short)f2bf(av.x); o[1] = (short)f2bf(av.y);
    o[2] = (short)f2bf(av.z); o[3] = (short)f2bf(av.w);
    o[4] = (short)f2bf(bv.x); o[5] = (short)f2bf(bv.y);
    o[6] = (short)f2bf(bv.z); o[7] = (short)f2bf(bv.w);
    *reinterpret_cast<short8*>(out + (size_t)i * 8) = o;
}

// ---------------------------------------------------------------------------
// QKV GEMM: 128x128 tile, BK=32, 3-buffer pipeline staged 2 ahead, counted
// vmcnt(4). LDS bank-swizzle: 16B slot ^= (row>>1)&3, on BOTH the
// pre-swizzled global source (linear gload_lds dest) and the ds_read slot.
// XCD-bijective grid swizzle (1440 blocks, chunk 180).
// ---------------------------------------------------------------------------
struct QkvArgs {
    const unsigned short* A;
    const unsigned short* w0[3];
    const unsigned short* w1[3];
    unsigned short* c[3];
};

__global__ __launch_bounds__(256)
void gemm_qkv(QkvArgs args)
{
    __shared__ unsigned short As[3][128 * 32];
    __shared__ unsigned short Bs[3][128 * 32];

    const int bid = blockIdx.x;
    const int swz = (bid & 7) * 180 + (bid >> 3);
    const int bm = swz % 20;
    int bn = swz / 20;                       // 0..71
    const int which = bn / 24; bn -= which * 24;

    const int rowbase = bm * 128, colbase = bn * 128;
    const unsigned short* __restrict__ A = args.A;
    const unsigned short* __restrict__ W = (rowbase < TXTLEN) ? args.w0[which] : args.w1[which];
    unsigned short* __restrict__ C = args.c[which];

    const int t = threadIdx.x, w = t >> 6, l = t & 63;
    const int lr = l & 15, lk = l >> 4;
    const int wr = (w >> 1) * 64, wc = (w & 1) * 64;

    f32x4 acc[4][4] = {};

    const int ssl = ((l & 3) ^ ((l >> 3) & 3)) * 8;   // pre-swizzled source slot
    const unsigned short* Ag = A + (size_t)(rowbase + w * 32 + (l >> 2)) * DIMC + ssl;
    const unsigned short* Wg = W + (size_t)(colbase + w * 32 + (l >> 2)) * DIMC + ssl;

    auto STAGE = [&](int buf, int k0) {
        gload16(Ag + k0,             &As[buf][w * 1024]);
        gload16(Ag + 16 * DIMC + k0, &As[buf][w * 1024 + 512]);
        gload16(Wg + k0,             &Bs[buf][w * 1024]);
        gload16(Wg + 16 * DIMC + k0, &Bs[buf][w * 1024 + 512]);
    };

    constexpr int NIT = DIMC / 32;   // 96
    STAGE(0, 0);
    STAGE(1, 32);

    const int rsl = (lk ^ ((lr >> 1) & 3)) * 8;   // swizzled ds_read slot
    int buf = 0;
    for (int it = 0; it < NIT; ++it) {
        asm volatile("s_waitcnt vmcnt(4)" ::: "memory");
        __builtin_amdgcn_s_barrier();
        asm volatile("" ::: "memory");

        {
            const int k2 = (it + 2 < NIT) ? (it + 2) : (NIT - 1);
            int b2 = buf + 2; if (b2 >= 3) b2 -= 3;
            STAGE(b2, k2 * 32);
        }

        short8 af[4], bf[4];
#pragma unroll
        for (int m = 0; m < 4; ++m)
            af[m] = *reinterpret_cast<const short8*>(&As[buf][(wr + m * 16 + lr) * 32 + rsl]);
#pragma unroll
        for (int n = 0; n < 4; ++n)
            bf[n] = *reinterpret_cast<const short8*>(&Bs[buf][(wc + n * 16 + lr) * 32 + rsl]);

        __builtin_amdgcn_s_setprio(1);
#pragma unroll
        for (int m = 0; m < 4; ++m)
#pragma unroll
            for (int n = 0; n < 4; ++n)
                acc[m][n] = __builtin_amdgcn_mfma_f32_16x16x32_bf16(af[m], bf[n], acc[m][n], 0, 0, 0);
        __builtin_amdgcn_s_setprio(0);

        buf = (buf + 1 == 3) ? 0 : buf + 1;
    }

#pragma unroll
    for (int m = 0; m < 4; ++m) {
#pragma unroll
        for (int r = 0; r < 4; ++r) {
            const int row = rowbase + wr + m * 16 + lk * 4 + r;
            unsigned short* crow = C + (size_t)row * DIMC + colbase + wc;
#pragma unroll
            for (int n = 0; n < 4; ++n)
                crow[n * 16 + lr] = f2bf(acc[m][n][r]);
        }
    }
}

// ---------------------------------------------------------------------------
// Output projection GEMM (f32 out, txt/img split), same pipeline + swizzle.
// ---------------------------------------------------------------------------
__global__ __launch_bounds__(256)
void gemm_out(const unsigned short* __restrict__ A, const unsigned short* __restrict__ W0,
              const unsigned short* __restrict__ W1, float* __restrict__ Ctxt,
              float* __restrict__ Cimg)
{
    __shared__ unsigned short As[3][128 * 32];
    __shared__ unsigned short Bs[3][128 * 32];

    const int bid = blockIdx.x;
    const int swz = (bid & 7) * 60 + (bid >> 3);
    const int bm = swz % 20;
    const int bn = swz / 20;                  // 0..23

    const int rowbase = bm * 128, colbase = bn * 128;
    const unsigned short* __restrict__ W = (rowbase < TXTLEN) ? W0 : W1;

    const int t = threadIdx.x, w = t >> 6, l = t & 63;
    const int lr = l & 15, lk = l >> 4;
    const int wr = (w >> 1) * 64, wc = (w & 1) * 64;

    f32x4 acc[4][4] = {};

    const int ssl = ((l & 3) ^ ((l >> 3) & 3)) * 8;
    const unsigned short* Ag = A + (size_t)(rowbase + w * 32 + (l >> 2)) * DIMC + ssl;
    const unsigned short* Wg = W + (size_t)(colbase + w * 32 + (l >> 2)) * DIMC + ssl;

    auto STAGE = [&](int buf, int k0) {
        gload16(Ag + k0,             &As[buf][w * 1024]);
        gload16(Ag + 16 * DIMC + k0, &As[buf][w * 1024 + 512]);
        gload16(Wg + k0,             &Bs[buf][w * 1024]);
        gload16(Wg + 16 * DIMC + k0, &Bs[buf][w * 1024 + 512]);
    };

    constexpr int NIT = DIMC / 32;
    STAGE(0, 0);
    STAGE(1, 32);

    const int rsl = (lk ^ ((lr >> 1) & 3)) * 8;
    int buf = 0;
    for (int it = 0; it < NIT; ++it) {
        asm volatile("s_waitcnt vmcnt(4)" ::: "memory");
        __builtin_amdgcn_s_barrier();
        asm volatile("" ::: "memory");

        {
            const int k2 = (it + 2 < NIT) ? (it + 2) : (NIT - 1);
            int b2 = buf + 2; if (b2 >= 3) b2 -= 3;
            STAGE(b2, k2 * 32);
        }

        short8 af[4], bf[4];
#pragma unroll
        for (int m = 0; m < 4; ++m)
            af[m] = *reinterpret_cast<const short8*>(&As[buf][(wr + m * 16 + lr) * 32 + rsl]);
#pragma unroll
        for (int n = 0; n < 4; ++n)
            bf[n] = *reinterpret_cast<const short8*>(&Bs[buf][(wc + n * 16 + lr) * 32 + rsl]);

        __builtin_amdgcn_s_setprio(1);
#pragma unroll
        for (int m = 0; m < 4; ++m)
#pragma unroll
            for (int n = 0; n < 4; ++n)
                acc[m][n] = __builtin_amdgcn_mfma_f32_16x16x32_bf16(af[m], bf[n], acc[m][n], 0, 0, 0);
        __builtin_amdgcn_s_setprio(0);

        buf = (buf + 1 == 3) ? 0 : buf + 1;
    }

    float* Cb; int rloc;
    if (rowbase < TXTLEN) { Cb = Ctxt; rloc = rowbase; }
    else                  { Cb = Cimg; rloc = rowbase - TXTLEN; }
#pragma unroll
    for (int m = 0; m < 4; ++m) {
#pragma unroll
        for (int r = 0; r < 4; ++r) {
            const int row = rloc + wr + m * 16 + lk * 4 + r;
            float* crow = Cb + (size_t)row * DIMC + colbase + wc;
#pragma unroll
            for (int n = 0; n < 4; ++n)
                crow[n * 16 + lr] = acc[m][n][r];
        }
    }
}

// ---------------------------------------------------------------------------
// RMSNorm + RoPE (+ 1/sqrt(HD) folded into Q), bf16 in/out.
// ---------------------------------------------------------------------------
__global__ __launch_bounds__(256)
void normrope(unsigned short* __restrict__ Q, unsigned short* __restrict__ K,
              const float* __restrict__ gq, const float* __restrict__ gk,
              const float* __restrict__ agq, const float* __restrict__ agk,
              const float* __restrict__ rc, const float* __restrict__ rs)
{
    const int wid  = (blockIdx.x << 2) + (threadIdx.x >> 6);
    const int lane = threadIdx.x & 63;
    const int s = wid / NHEADS, h = wid - s * NHEADS;
    const bool img = (s >= TXTLEN);
    const float* gq_ = img ? gq : agq;
    const float* gk_ = img ? gk : agk;

    const size_t base = (size_t)s * DIMC + h * HD + lane * 2;
    const float2 c2  = *reinterpret_cast<const float2*>(rc + (size_t)s * HD + lane * 2);
    const float2 s2  = *reinterpret_cast<const float2*>(rs + (size_t)s * HD + lane * 2);
    const float2 gqv = *reinterpret_cast<const float2*>(gq_ + lane * 2);
    const float2 gkv = *reinterpret_cast<const float2*>(gk_ + lane * 2);

    {
        unsigned pr = *reinterpret_cast<unsigned*>(Q + base);
        float vx = bf2f((unsigned short)(pr & 0xffff));
        float vy = bf2f((unsigned short)(pr >> 16));
        float ss = vx * vx + vy * vy;
#pragma unroll
        for (int off = 1; off < 64; off <<= 1) ss += __shfl_xor(ss, off);
        const float rr = rsqrtf(ss * (1.f / HD) + 1e-6f);
        const float txv = vx * rr * gqv.x, tyv = vy * rr * gqv.y;
        const float qs = 0.08838834764831845f;
        const float ox = (txv * c2.x - tyv * s2.x) * qs;
        const float oy = (tyv * c2.y + txv * s2.y) * qs;
        *reinterpret_cast<unsigned*>(Q + base) = (unsigned)f2bf(ox) | ((unsigned)f2bf(oy) << 16);
    }
    {
        unsigned pr = *reinterpret_cast<unsigned*>(K + base);
        float vx = bf2f((unsigned short)(pr & 0xffff));
        float vy = bf2f((unsigned short)(pr >> 16));
        float ss = vx * vx + vy * vy;
#pragma unroll
        for (int off = 1; off < 64; off <<= 1) ss += __shfl_xor(ss, off);
        const float rr = rsqrtf(ss * (1.f / HD) + 1e-6f);
        const float txv = vx * rr * gkv.x, tyv = vy * rr * gkv.y;
        const float ox = txv * c2.x - tyv * s2.x;
        const float oy = tyv * c2.y + txv * s2.y;
        *reinterpret_cast<unsigned*>(K + base) = (unsigned)f2bf(ox) | ((unsigned)f2bf(oy) << 16);
    }
}

// ---------------------------------------------------------------------------
// V[2560][3072] -> Vt[24][128][2560]
// ---------------------------------------------------------------------------
__global__ __launch_bounds__(256)
void transpose_v(const unsigned short* __restrict__ V, unsigned short* __restrict__ Vt)
{
    __shared__ unsigned short Ts[64][136];
    const int kt = blockIdx.x, h = blockIdx.y;
    const int t = threadIdx.x;
#pragma unroll
    for (int p = 0; p < 4; ++p) {
        const int row = p * 16 + (t >> 4);
        const int col = (t & 15) * 8;
        *reinterpret_cast<short8*>(&Ts[row][col]) =
            *reinterpret_cast<const short8*>(V + (size_t)(kt * 64 + row) * DIMC + h * HD + col);
    }
    __syncthreads();
    const int d = t >> 1, kh = t & 1;
    unsigned short* dst = Vt + (size_t)h * HD * SEQ + (size_t)d * SEQ + kt * 64 + kh * 32;
#pragma unroll
    for (int j4 = 0; j4 < 4; ++j4) {
        short8 o;
#pragma unroll
        for (int j = 0; j < 8; ++j) o[j] = (short)Ts[kh * 32 + j4 * 8 + j][d];
        *reinterpret_cast<short8*>(dst + j4 * 8) = o;
    }
}

// ---------------------------------------------------------------------------
// Flash attention: 128 q-rows x 1 head per block, 8 waves, XCD-swizzled grid.
// K/V double-buffered (XOR-swizzled via pre-swizzled global src).
// T5 setprio + T13 defer-max.
// ---------------------------------------------------------------------------
__global__ __launch_bounds__(512)
void attn_mfma(const unsigned short* __restrict__ Q, const unsigned short* __restrict__ K,
               const unsigned short* __restrict__ Vt, unsigned short* __restrict__ O)
{
    __shared__ unsigned short Ks[2][64 * 128];   // [kv][d], slot^=(kv&7)
    __shared__ unsigned short Vs[2][128 * 64];   // [d][kv], slot^=(d&7)
    __shared__ unsigned short Ps[8][16 * 64];    // per-wave P, swizzled

    const int bid = blockIdx.x;
    const int swz = (bid & 7) * 60 + (bid >> 3);
    const int bq = swz % 20;
    const int h  = swz / 20;

    const int t = threadIdx.x, w = t >> 6, l = t & 63;
    const int lr = l & 15, lk = l >> 4;
    const int q0 = bq * 128 + w * 16;

    short8 qf[4];
#pragma unroll
    for (int kk = 0; kk < 4; ++kk)
        qf[kk] = *reinterpret_cast<const short8*>(
            Q + (size_t)(q0 + lr) * DIMC + h * HD + kk * 32 + lk * 8);

    f32x4 oacc[8] = {};
    float mrow[4] = {-1e30f, -1e30f, -1e30f, -1e30f};
    float lrow[4] = {};

    const unsigned short* Kg[2];
    const unsigned short* Vg[2];
#pragma unroll
    for (int i = 0; i < 2; ++i) {
        const int kr = w * 8 + i * 4 + (l >> 4);
        Kg[i] = K + (size_t)kr * DIMC + h * HD + (((l & 15) ^ (kr & 7)) * 8);
        const int vr = w * 16 + i * 8 + (l >> 3);
        Vg[i] = Vt + (size_t)h * HD * SEQ + (size_t)vr * SEQ + (((l & 7) ^ (vr & 7)) * 8);
    }

    auto STAGE = [&](int buf, int kv0) {
#pragma unroll
        for (int i = 0; i < 2; ++i) {
            gload16(Kg[i] + (size_t)kv0 * DIMC, &Ks[buf][(w * 8 + i * 4) * 128]);
            gload16(Vg[i] + kv0,                &Vs[buf][(w * 16 + i * 8) * 64]);
        }
    };

    STAGE(0, 0);

    constexpr int NT = SEQ / 64;  // 40
    for (int kt = 0; kt < NT; ++kt) {
        const int buf = kt & 1;
        __syncthreads();
        if (kt + 1 < NT) STAGE(buf ^ 1, (kt + 1) * 64);

        // S = Q K^T
        f32x4 sf[4] = {};
        __builtin_amdgcn_s_setprio(1);
#pragma unroll
        for (int nf = 0; nf < 4; ++nf) {
            const int row = nf * 16 + lr;
            const int sw = (row & 7) << 3;
#pragma unroll
            for (int kk = 0; kk < 4; ++kk) {
                short8 bfr = *reinterpret_cast<const short8*>(
                    &Ks[buf][row * 128 + ((kk * 32 + lk * 8) ^ sw)]);
                sf[nf] = __builtin_amdgcn_mfma_f32_16x16x32_bf16(qf[kk], bfr, sf[nf], 0, 0, 0);
            }
        }
        __builtin_amdgcn_s_setprio(0);

        // online softmax with defer-max (T13)
        float mxr[4];
#pragma unroll
        for (int r = 0; r < 4; ++r) {
            float mx = fmaxf(fmaxf(sf[0][r], sf[1][r]), fmaxf(sf[2][r], sf[3][r]));
#pragma unroll
            for (int off = 1; off < 16; off <<= 1) mx = fmaxf(mx, __shfl_xor(mx, off));
            mxr[r] = mx;
        }
        const float need = fmaxf(fmaxf(mxr[0] - mrow[0], mxr[1] - mrow[1]),
                                 fmaxf(mxr[2] - mrow[2], mxr[3] - mrow[3]));
        if (!__all(need <= 8.0f)) {
#pragma unroll
            for (int r = 0; r < 4; ++r) {
                const float mn = fmaxf(mrow[r], mxr[r]);
                const float alpha = __expf(mrow[r] - mn);
                mrow[r] = mn;
                lrow[r] *= alpha;
#pragma unroll
                for (int nf = 0; nf < 8; ++nf) oacc[nf][r] *= alpha;
            }
        }
#pragma unroll
        for (int r = 0; r < 4; ++r) {
            float ps = 0.f;
#pragma unroll
            for (int nf = 0; nf < 4; ++nf) {
                const float p = __expf(sf[nf][r] - mrow[r]);
                sf[nf][r] = p;
                ps += p;
            }
#pragma unroll
            for (int off = 1; off < 16; off <<= 1) ps += __shfl_xor(ps, off);
            lrow[r] += ps;
        }

        // P -> per-wave LDS (swizzled); same-wave producer/consumer
#pragma unroll
        for (int r = 0; r < 4; ++r) {
            const int prow = lk * 4 + r;
            const int sw = (prow & 7) << 3;
#pragma unroll
            for (int nf = 0; nf < 4; ++nf) {
                const int col = nf * 16 + lr;
                Ps[w][prow * 64 + (col ^ sw)] = f2bf(sf[nf][r]);
            }
        }

        // O += P V
        __builtin_amdgcn_s_setprio(1);
#pragma unroll
        for (int ks = 0; ks < 2; ++ks) {
            short8 pa = *reinterpret_cast<const short8*>(
                &Ps[w][lr * 64 + ((ks * 32 + lk * 8) ^ ((lr & 7) << 3))]);
#pragma unroll
            for (int nf = 0; nf < 8; ++nf) {
                const int vrow = nf * 16 + lr;
                short8 vf = *reinterpret_cast<const short8*>(
                    &Vs[buf][vrow * 64 + ((ks * 32 + lk * 8) ^ ((vrow & 7) << 3))]);
                oacc[nf] = __builtin_amdgcn_mfma_f32_16x16x32_bf16(pa, vf, oacc[nf], 0, 0, 0);
            }
        }
        __builtin_amdgcn_s_setprio(0);
    }

    float inv[4];
#pragma unroll
    for (int r = 0; r < 4; ++r) inv[r] = 1.f / lrow[r];
#pragma unroll
    for (int nf = 0; nf < 8; ++nf)
#pragma unroll
        for (int r = 0; r < 4; ++r)
            O[(size_t)(q0 + lk * 4 + r) * DIMC + h * HD + nf * 16 + lr] = f2bf(oacc[nf][r] * inv[r]);
}

// ---------------------------------------------------------------------------
extern "C" void kernel_launch(void* const* d_in, const int* in_sizes, int n_in,
                              void* d_out, int out_size, void* d_ws, size_t ws_size,
                              hipStream_t stream)
{
    const float* x    = (const float*)d_in[0];
    const float* ctx  = (const float*)d_in[1];
    const float* rc   = (const float*)d_in[2];
    const float* rs   = (const float*)d_in[3];
    const float* wq   = (const float*)d_in[4];
    const float* wk   = (const float*)d_in[5];
    const float* wv   = (const float*)d_in[6];
    const float* gq   = (const float*)d_in[7];
    const float* gk   = (const float*)d_in[8];
    const float* wo   = (const float*)d_in[9];
    const float* awq  = (const float*)d_in[10];
    const float* awk  = (const float*)d_in[11];
    const float* awv  = (const float*)d_in[12];
    const float* agq  = (const float*)d_in[13];
    const float* agk  = (const float*)d_in[14];
    const float* awo  = (const float*)d_in[15];

    unsigned short* wsp = (unsigned short*)d_ws;
    const size_t SZ  = (size_t)SEQ * DIMC;
    const size_t WSZ = (size_t)DIMC * DIMC;
    unsigned short* XC  = wsp;
    unsigned short* Qb  = XC + SZ;
    unsigned short* Kb  = Qb + SZ;
    unsigned short* Vb  = Kb + SZ;
    unsigned short* Vtb = Vb + SZ;
    unsigned short* Ob  = Vtb + SZ;
    unsigned short* Wc  = Ob + SZ;  // 8 weights: awq, wq, awk, wk, awv, wv, awo, wo

    {
        C2 c2a;
        c2a.src[0] = ctx; c2a.n8[0] = (size_t)TXTLEN * DIMC / 8; c2a.dst[0] = XC;
        c2a.src[1] = x;   c2a.n8[1] = (size_t)IMGLEN * DIMC / 8; c2a.dst[1] = XC + (size_t)TXTLEN * DIMC;
        const int maxb = (int)((c2a.n8[1] + 255) / 256);
        castk2<<<dim3(maxb, 2), dim3(256), 0, stream>>>(c2a);
    }
    {
        W8 w8;
        w8.src[0] = awq; w8.src[1] = wq; w8.src[2] = awk; w8.src[3] = wk;
        w8.src[4] = awv; w8.src[5] = wv; w8.src[6] = awo; w8.src[7] = wo;
        const int n8 = (int)(WSZ / 8);
        castw<<<dim3((n8 + 255) / 256, 8), dim3(256), 0, stream>>>(w8, Wc, n8, WSZ);
    }

    QkvArgs qa;
    qa.A = XC;
    qa.w0[0] = Wc + 0 * WSZ; qa.w1[0] = Wc + 1 * WSZ; qa.c[0] = Qb;
    qa.w0[1] = Wc + 2 * WSZ; qa.w1[1] = Wc + 3 * WSZ; qa.c[1] = Kb;
    qa.w0[2] = Wc + 4 * WSZ; qa.w1[2] = Wc + 5 * WSZ; qa.c[2] = Vb;
    gemm_qkv<<<dim3(1440), dim3(256), 0, stream>>>(qa);

    normrope<<<dim3(SEQ * NHEADS / 4), dim3(256), 0, stream>>>(Qb, Kb, gq, gk, agq, agk, rc, rs);

    transpose_v<<<dim3(SEQ / 64, NHEADS), dim3(256), 0, stream>>>(Vb, Vtb);

    attn_mfma<<<dim3(480), dim3(512), 0, stream>>>(Qb, Kb, Vtb, Ob);

    float* out = (float*)d_out;
    gemm_out<<<dim3(480), dim3(256), 0, stream>>>(
        Ob, Wc + 6 * WSZ, Wc + 7 * WSZ, out + (size_t)IMGLEN * DIMC, out);
}

// Round 19
// 529.296 us; speedup vs baseline: 1.0140x; 1.0046x over previous
//
#include <hip/hip_runtime.h>
#include <hip/hip_bf16.h>

#define DIMC 3072
#define NHEADS 24
#define HD 128
#define SEQ 2560
#define TXTLEN 512
#define IMGLEN 2048

using short8 = __attribute__((ext_vector_type(8))) short;
using f32x4  = __attribute__((ext_vector_type(4))) float;

static __device__ __forceinline__ float bf2f(unsigned short u) {
    unsigned v = ((unsigned)u) << 16;
    return __builtin_bit_cast(float, v);
}
static __device__ __forceinline__ unsigned short f2bf(float f) {
    unsigned u = __builtin_bit_cast(unsigned, f);
    return (unsigned short)((u + 0x7FFFu + ((u >> 16) & 1u)) >> 16);
}
static __device__ __forceinline__ void gload16(const void* g, void* l) {
    __builtin_amdgcn_global_load_lds((const __attribute__((address_space(1))) unsigned int*)g,
                                     (__attribute__((address_space(3))) unsigned int*)l,
                                     16, 0, 0);
}

// ---------------------------------------------------------------------------
// f32 -> bf16 casts: activations (2 sources, one dispatch) and 8 weights.
// ---------------------------------------------------------------------------
struct C2 { const float* src[2]; size_t n8[2]; unsigned short* dst[2]; };
__global__ __launch_bounds__(256)
void castk2(C2 a)
{
    const int which = blockIdx.y;
    const size_t i = (size_t)blockIdx.x * 256 + threadIdx.x;
    if (i >= a.n8[which]) return;
    const float* in = a.src[which];
    unsigned short* out = a.dst[which];
    const float4 av = *reinterpret_cast<const float4*>(in + i * 8);
    const float4 bv = *reinterpret_cast<const float4*>(in + i * 8 + 4);
    short8 o;
    o[0] = (short)f2bf(av.x); o[1] = (short)f2bf(av.y);
    o[2] = (short)f2bf(av.z); o[3] = (short)f2bf(av.w);
    o[4] = (short)f2bf(bv.x); o[5] = (short)f2bf(bv.y);
    o[6] = (short)f2bf(bv.z); o[7] = (short)f2bf(bv.w);
    *reinterpret_cast<short8*>(out + i * 8) = o;
}

struct W8 { const float* src[8]; };
__global__ __launch_bounds__(256)
void castw(W8 a, unsigned short* __restrict__ dstbase, int n8, size_t wsz)
{
    const int i = blockIdx.x * 256 + threadIdx.x;
    if (i >= n8) return;
    const float* in = a.src[blockIdx.y];
    unsigned short* out = dstbase + (size_t)blockIdx.y * wsz;
    const float4 av = *reinterpret_cast<const float4*>(in + (size_t)i * 8);
    const float4 bv = *reinterpret_cast<const float4*>(in + (size_t)i * 8 + 4);
    short8 o;
    o[0] = (short)f2bf(av.x); o[1] = (short)f2bf(av.y);
    o[2] = (short)f2bf(av.z); o[3] = (short)f2bf(av.w);
    o[4] = (short)f2bf(bv.x); o[5] = (short)f2bf(bv.y);
    o[6] = (short)f2bf(bv.z); o[7] = (short)f2bf(bv.w);
    *reinterpret_cast<short8*>(out + (size_t)i * 8) = o;
}

// ---------------------------------------------------------------------------
// QKV GEMM: 128x128 tile, BK=32, 3-buffer pipeline staged 2 ahead, counted
// vmcnt(4). LDS bank-swizzle: 16B slot ^= (row>>1)&3, on BOTH the
// pre-swizzled global source (linear gload_lds dest) and the ds_read slot.
// XCD-bijective grid swizzle (1440 blocks, chunk 180).
// ---------------------------------------------------------------------------
struct QkvArgs {
    const unsigned short* A;
    const unsigned short* w0[3];
    const unsigned short* w1[3];
    unsigned short* c[3];
};

__global__ __launch_bounds__(256)
void gemm_qkv(QkvArgs args)
{
    __shared__ unsigned short As[3][128 * 32];
    __shared__ unsigned short Bs[3][128 * 32];

    const int bid = blockIdx.x;
    const int swz = (bid & 7) * 180 + (bid >> 3);
    const int bm = swz % 20;
    int bn = swz / 20;                       // 0..71
    const int which = bn / 24; bn -= which * 24;

    const int rowbase = bm * 128, colbase = bn * 128;
    const unsigned short* __restrict__ A = args.A;
    const unsigned short* __restrict__ W = (rowbase < TXTLEN) ? args.w0[which] : args.w1[which];
    unsigned short* __restrict__ C = args.c[which];

    const int t = threadIdx.x, w = t >> 6, l = t & 63;
    const int lr = l & 15, lk = l >> 4;
    const int wr = (w >> 1) * 64, wc = (w & 1) * 64;

    f32x4 acc[4][4] = {};

    const int ssl = ((l & 3) ^ ((l >> 3) & 3)) * 8;   // pre-swizzled source slot
    const unsigned short* Ag = A + (size_t)(rowbase + w * 32 + (l >> 2)) * DIMC + ssl;
    const unsigned short* Wg = W + (size_t)(colbase + w * 32 + (l >> 2)) * DIMC + ssl;

    auto STAGE = [&](int buf, int k0) {
        gload16(Ag + k0,             &As[buf][w * 1024]);
        gload16(Ag + 16 * DIMC + k0, &As[buf][w * 1024 + 512]);
        gload16(Wg + k0,             &Bs[buf][w * 1024]);
        gload16(Wg + 16 * DIMC + k0, &Bs[buf][w * 1024 + 512]);
    };

    constexpr int NIT = DIMC / 32;   // 96
    STAGE(0, 0);
    STAGE(1, 32);

    const int rsl = (lk ^ ((lr >> 1) & 3)) * 8;   // swizzled ds_read slot
    int buf = 0;
    for (int it = 0; it < NIT; ++it) {
        asm volatile("s_waitcnt vmcnt(4)" ::: "memory");
        __builtin_amdgcn_s_barrier();
        asm volatile("" ::: "memory");

        {
            const int k2 = (it + 2 < NIT) ? (it + 2) : (NIT - 1);
            int b2 = buf + 2; if (b2 >= 3) b2 -= 3;
            STAGE(b2, k2 * 32);
        }

        short8 af[4], bf[4];
#pragma unroll
        for (int m = 0; m < 4; ++m)
            af[m] = *reinterpret_cast<const short8*>(&As[buf][(wr + m * 16 + lr) * 32 + rsl]);
#pragma unroll
        for (int n = 0; n < 4; ++n)
            bf[n] = *reinterpret_cast<const short8*>(&Bs[buf][(wc + n * 16 + lr) * 32 + rsl]);

        __builtin_amdgcn_s_setprio(1);
#pragma unroll
        for (int m = 0; m < 4; ++m)
#pragma unroll
            for (int n = 0; n < 4; ++n)
                acc[m][n] = __builtin_amdgcn_mfma_f32_16x16x32_bf16(af[m], bf[n], acc[m][n], 0, 0, 0);
        __builtin_amdgcn_s_setprio(0);

        buf = (buf + 1 == 3) ? 0 : buf + 1;
    }

#pragma unroll
    for (int m = 0; m < 4; ++m) {
#pragma unroll
        for (int r = 0; r < 4; ++r) {
            const int row = rowbase + wr + m * 16 + lk * 4 + r;
            unsigned short* crow = C + (size_t)row * DIMC + colbase + wc;
#pragma unroll
            for (int n = 0; n < 4; ++n)
                crow[n * 16 + lr] = f2bf(acc[m][n][r]);
        }
    }
}

// ---------------------------------------------------------------------------
// Output projection GEMM (f32 out, txt/img split), same pipeline + swizzle.
// ---------------------------------------------------------------------------
__global__ __launch_bounds__(256)
void gemm_out(const unsigned short* __restrict__ A, const unsigned short* __restrict__ W0,
              const unsigned short* __restrict__ W1, float* __restrict__ Ctxt,
              float* __restrict__ Cimg)
{
    __shared__ unsigned short As[3][128 * 32];
    __shared__ unsigned short Bs[3][128 * 32];

    const int bid = blockIdx.x;
    const int swz = (bid & 7) * 60 + (bid >> 3);
    const int bm = swz % 20;
    const int bn = swz / 20;                  // 0..23

    const int rowbase = bm * 128, colbase = bn * 128;
    const unsigned short* __restrict__ W = (rowbase < TXTLEN) ? W0 : W1;

    const int t = threadIdx.x, w = t >> 6, l = t & 63;
    const int lr = l & 15, lk = l >> 4;
    const int wr = (w >> 1) * 64, wc = (w & 1) * 64;

    f32x4 acc[4][4] = {};

    const int ssl = ((l & 3) ^ ((l >> 3) & 3)) * 8;
    const unsigned short* Ag = A + (size_t)(rowbase + w * 32 + (l >> 2)) * DIMC + ssl;
    const unsigned short* Wg = W + (size_t)(colbase + w * 32 + (l >> 2)) * DIMC + ssl;

    auto STAGE = [&](int buf, int k0) {
        gload16(Ag + k0,             &As[buf][w * 1024]);
        gload16(Ag + 16 * DIMC + k0, &As[buf][w * 1024 + 512]);
        gload16(Wg + k0,             &Bs[buf][w * 1024]);
        gload16(Wg + 16 * DIMC + k0, &Bs[buf][w * 1024 + 512]);
    };

    constexpr int NIT = DIMC / 32;
    STAGE(0, 0);
    STAGE(1, 32);

    const int rsl = (lk ^ ((lr >> 1) & 3)) * 8;
    int buf = 0;
    for (int it = 0; it < NIT; ++it) {
        asm volatile("s_waitcnt vmcnt(4)" ::: "memory");
        __builtin_amdgcn_s_barrier();
        asm volatile("" ::: "memory");

        {
            const int k2 = (it + 2 < NIT) ? (it + 2) : (NIT - 1);
            int b2 = buf + 2; if (b2 >= 3) b2 -= 3;
            STAGE(b2, k2 * 32);
        }

        short8 af[4], bf[4];
#pragma unroll
        for (int m = 0; m < 4; ++m)
            af[m] = *reinterpret_cast<const short8*>(&As[buf][(wr + m * 16 + lr) * 32 + rsl]);
#pragma unroll
        for (int n = 0; n < 4; ++n)
            bf[n] = *reinterpret_cast<const short8*>(&Bs[buf][(wc + n * 16 + lr) * 32 + rsl]);

        __builtin_amdgcn_s_setprio(1);
#pragma unroll
        for (int m = 0; m < 4; ++m)
#pragma unroll
            for (int n = 0; n < 4; ++n)
                acc[m][n] = __builtin_amdgcn_mfma_f32_16x16x32_bf16(af[m], bf[n], acc[m][n], 0, 0, 0);
        __builtin_amdgcn_s_setprio(0);

        buf = (buf + 1 == 3) ? 0 : buf + 1;
    }

    float* Cb; int rloc;
    if (rowbase < TXTLEN) { Cb = Ctxt; rloc = rowbase; }
    else                  { Cb = Cimg; rloc = rowbase - TXTLEN; }
#pragma unroll
    for (int m = 0; m < 4; ++m) {
#pragma unroll
        for (int r = 0; r < 4; ++r) {
            const int row = rloc + wr + m * 16 + lk * 4 + r;
            float* crow = Cb + (size_t)row * DIMC + colbase + wc;
#pragma unroll
            for (int n = 0; n < 4; ++n)
                crow[n * 16 + lr] = acc[m][n][r];
        }
    }
}

// ---------------------------------------------------------------------------
// Fused normrope + transpose_v: one dispatch, blockIdx-partitioned.
// bid < 15360: RMSNorm+RoPE on Q,K (one wave per (s,h) row).
// bid >= 15360: V[2560][3072] -> Vt[24][128][2560] tile transpose.
// The two paths touch disjoint buffers; merging removes one launch/drain.
// ---------------------------------------------------------------------------
#define NR_BLOCKS (SEQ * NHEADS / 4)   // 15360

__global__ __launch_bounds__(256)
void normrope_transpose(unsigned short* __restrict__ Q, unsigned short* __restrict__ K,
                        const float* __restrict__ gq, const float* __restrict__ gk,
                        const float* __restrict__ agq, const float* __restrict__ agk,
                        const float* __restrict__ rc, const float* __restrict__ rs,
                        const unsigned short* __restrict__ V, unsigned short* __restrict__ Vt)
{
    __shared__ unsigned short Ts[64][136];
    const int bid = blockIdx.x;

    if (bid < NR_BLOCKS) {
        // ---- normrope path ----
        const int wid  = (bid << 2) + (threadIdx.x >> 6);
        const int lane = threadIdx.x & 63;
        const int s = wid / NHEADS, h = wid - s * NHEADS;
        const bool img = (s >= TXTLEN);
        const float* gq_ = img ? gq : agq;
        const float* gk_ = img ? gk : agk;

        const size_t base = (size_t)s * DIMC + h * HD + lane * 2;
        const float2 c2  = *reinterpret_cast<const float2*>(rc + (size_t)s * HD + lane * 2);
        const float2 s2  = *reinterpret_cast<const float2*>(rs + (size_t)s * HD + lane * 2);
        const float2 gqv = *reinterpret_cast<const float2*>(gq_ + lane * 2);
        const float2 gkv = *reinterpret_cast<const float2*>(gk_ + lane * 2);

        {
            unsigned pr = *reinterpret_cast<unsigned*>(Q + base);
            float vx = bf2f((unsigned short)(pr & 0xffff));
            float vy = bf2f((unsigned short)(pr >> 16));
            float ss = vx * vx + vy * vy;
#pragma unroll
            for (int off = 1; off < 64; off <<= 1) ss += __shfl_xor(ss, off);
            const float rr = rsqrtf(ss * (1.f / HD) + 1e-6f);
            const float txv = vx * rr * gqv.x, tyv = vy * rr * gqv.y;
            const float qs = 0.08838834764831845f;
            const float ox = (txv * c2.x - tyv * s2.x) * qs;
            const float oy = (tyv * c2.y + txv * s2.y) * qs;
            *reinterpret_cast<unsigned*>(Q + base) = (unsigned)f2bf(ox) | ((unsigned)f2bf(oy) << 16);
        }
        {
            unsigned pr = *reinterpret_cast<unsigned*>(K + base);
            float vx = bf2f((unsigned short)(pr & 0xffff));
            float vy = bf2f((unsigned short)(pr >> 16));
            float ss = vx * vx + vy * vy;
#pragma unroll
            for (int off = 1; off < 64; off <<= 1) ss += __shfl_xor(ss, off);
            const float rr = rsqrtf(ss * (1.f / HD) + 1e-6f);
            const float txv = vx * rr * gkv.x, tyv = vy * rr * gkv.y;
            const float ox = txv * c2.x - tyv * s2.x;
            const float oy = tyv * c2.y + txv * s2.y;
            *reinterpret_cast<unsigned*>(K + base) = (unsigned)f2bf(ox) | ((unsigned)f2bf(oy) << 16);
        }
    } else {
        // ---- transpose_v path ----
        const int b2 = bid - NR_BLOCKS;
        const int kt = b2 % (SEQ / 64);
        const int h  = b2 / (SEQ / 64);
        const int t = threadIdx.x;
#pragma unroll
        for (int p = 0; p < 4; ++p) {
            const int row = p * 16 + (t >> 4);
            const int col = (t & 15) * 8;
            *reinterpret_cast<short8*>(&Ts[row][col]) =
                *reinterpret_cast<const short8*>(V + (size_t)(kt * 64 + row) * DIMC + h * HD + col);
        }
        __syncthreads();
        const int d = t >> 1, kh = t & 1;
        unsigned short* dst = Vt + (size_t)h * HD * SEQ + (size_t)d * SEQ + kt * 64 + kh * 32;
#pragma unroll
        for (int j4 = 0; j4 < 4; ++j4) {
            short8 o;
#pragma unroll
            for (int j = 0; j < 8; ++j) o[j] = (short)Ts[kh * 32 + j4 * 8 + j][d];
            *reinterpret_cast<short8*>(dst + j4 * 8) = o;
        }
    }
}

// ---------------------------------------------------------------------------
// Flash attention: 128 q-rows x 1 head per block, 8 waves, XCD-swizzled grid.
// K/V double-buffered (XOR-swizzled via pre-swizzled global src).
// T5 setprio + T13 defer-max.
// ---------------------------------------------------------------------------
__global__ __launch_bounds__(512)
void attn_mfma(const unsigned short* __restrict__ Q, const unsigned short* __restrict__ K,
               const unsigned short* __restrict__ Vt, unsigned short* __restrict__ O)
{
    __shared__ unsigned short Ks[2][64 * 128];   // [kv][d], slot^=(kv&7)
    __shared__ unsigned short Vs[2][128 * 64];   // [d][kv], slot^=(d&7)
    __shared__ unsigned short Ps[8][16 * 64];    // per-wave P, swizzled

    const int bid = blockIdx.x;
    const int swz = (bid & 7) * 60 + (bid >> 3);
    const int bq = swz % 20;
    const int h  = swz / 20;

    const int t = threadIdx.x, w = t >> 6, l = t & 63;
    const int lr = l & 15, lk = l >> 4;
    const int q0 = bq * 128 + w * 16;

    short8 qf[4];
#pragma unroll
    for (int kk = 0; kk < 4; ++kk)
        qf[kk] = *reinterpret_cast<const short8*>(
            Q + (size_t)(q0 + lr) * DIMC + h * HD + kk * 32 + lk * 8);

    f32x4 oacc[8] = {};
    float mrow[4] = {-1e30f, -1e30f, -1e30f, -1e30f};
    float lrow[4] = {};

    const unsigned short* Kg[2];
    const unsigned short* Vg[2];
#pragma unroll
    for (int i = 0; i < 2; ++i) {
        const int kr = w * 8 + i * 4 + (l >> 4);
        Kg[i] = K + (size_t)kr * DIMC + h * HD + (((l & 15) ^ (kr & 7)) * 8);
        const int vr = w * 16 + i * 8 + (l >> 3);
        Vg[i] = Vt + (size_t)h * HD * SEQ + (size_t)vr * SEQ + (((l & 7) ^ (vr & 7)) * 8);
    }

    auto STAGE = [&](int buf, int kv0) {
#pragma unroll
        for (int i = 0; i < 2; ++i) {
            gload16(Kg[i] + (size_t)kv0 * DIMC, &Ks[buf][(w * 8 + i * 4) * 128]);
            gload16(Vg[i] + kv0,                &Vs[buf][(w * 16 + i * 8) * 64]);
        }
    };

    STAGE(0, 0);

    constexpr int NT = SEQ / 64;  // 40
    for (int kt = 0; kt < NT; ++kt) {
        const int buf = kt & 1;
        __syncthreads();
        if (kt + 1 < NT) STAGE(buf ^ 1, (kt + 1) * 64);

        // S = Q K^T
        f32x4 sf[4] = {};
        __builtin_amdgcn_s_setprio(1);
#pragma unroll
        for (int nf = 0; nf < 4; ++nf) {
            const int row = nf * 16 + lr;
            const int sw = (row & 7) << 3;
#pragma unroll
            for (int kk = 0; kk < 4; ++kk) {
                short8 bfr = *reinterpret_cast<const short8*>(
                    &Ks[buf][row * 128 + ((kk * 32 + lk * 8) ^ sw)]);
                sf[nf] = __builtin_amdgcn_mfma_f32_16x16x32_bf16(qf[kk], bfr, sf[nf], 0, 0, 0);
            }
        }
        __builtin_amdgcn_s_setprio(0);

        // online softmax with defer-max (T13)
        float mxr[4];
#pragma unroll
        for (int r = 0; r < 4; ++r) {
            float mx = fmaxf(fmaxf(sf[0][r], sf[1][r]), fmaxf(sf[2][r], sf[3][r]));
#pragma unroll
            for (int off = 1; off < 16; off <<= 1) mx = fmaxf(mx, __shfl_xor(mx, off));
            mxr[r] = mx;
        }
        const float need = fmaxf(fmaxf(mxr[0] - mrow[0], mxr[1] - mrow[1]),
                                 fmaxf(mxr[2] - mrow[2], mxr[3] - mrow[3]));
        if (!__all(need <= 8.0f)) {
#pragma unroll
            for (int r = 0; r < 4; ++r) {
                const float mn = fmaxf(mrow[r], mxr[r]);
                const float alpha = __expf(mrow[r] - mn);
                mrow[r] = mn;
                lrow[r] *= alpha;
#pragma unroll
                for (int nf = 0; nf < 8; ++nf) oacc[nf][r] *= alpha;
            }
        }
#pragma unroll
        for (int r = 0; r < 4; ++r) {
            float ps = 0.f;
#pragma unroll
            for (int nf = 0; nf < 4; ++nf) {
                const float p = __expf(sf[nf][r] - mrow[r]);
                sf[nf][r] = p;
                ps += p;
            }
#pragma unroll
            for (int off = 1; off < 16; off <<= 1) ps += __shfl_xor(ps, off);
            lrow[r] += ps;
        }

        // P -> per-wave LDS (swizzled); same-wave producer/consumer
#pragma unroll
        for (int r = 0; r < 4; ++r) {
            const int prow = lk * 4 + r;
            const int sw = (prow & 7) << 3;
#pragma unroll
            for (int nf = 0; nf < 4; ++nf) {
                const int col = nf * 16 + lr;
                Ps[w][prow * 64 + (col ^ sw)] = f2bf(sf[nf][r]);
            }
        }

        // O += P V
        __builtin_amdgcn_s_setprio(1);
#pragma unroll
        for (int ks = 0; ks < 2; ++ks) {
            short8 pa = *reinterpret_cast<const short8*>(
                &Ps[w][lr * 64 + ((ks * 32 + lk * 8) ^ ((lr & 7) << 3))]);
#pragma unroll
            for (int nf = 0; nf < 8; ++nf) {
                const int vrow = nf * 16 + lr;
                short8 vf = *reinterpret_cast<const short8*>(
                    &Vs[buf][vrow * 64 + ((ks * 32 + lk * 8) ^ ((vrow & 7) << 3))]);
                oacc[nf] = __builtin_amdgcn_mfma_f32_16x16x32_bf16(pa, vf, oacc[nf], 0, 0, 0);
            }
        }
        __builtin_amdgcn_s_setprio(0);
    }

    float inv[4];
#pragma unroll
    for (int r = 0; r < 4; ++r) inv[r] = 1.f / lrow[r];
#pragma unroll
    for (int nf = 0; nf < 8; ++nf)
#pragma unroll
        for (int r = 0; r < 4; ++r)
            O[(size_t)(q0 + lk * 4 + r) * DIMC + h * HD + nf * 16 + lr] = f2bf(oacc[nf][r] * inv[r]);
}

// ---------------------------------------------------------------------------
extern "C" void kernel_launch(void* const* d_in, const int* in_sizes, int n_in,
                              void* d_out, int out_size, void* d_ws, size_t ws_size,
                              hipStream_t stream)
{
    const float* x    = (const float*)d_in[0];
    const float* ctx  = (const float*)d_in[1];
    const float* rc   = (const float*)d_in[2];
    const float* rs   = (const float*)d_in[3];
    const float* wq   = (const float*)d_in[4];
    const float* wk   = (const float*)d_in[5];
    const float* wv   = (const float*)d_in[6];
    const float* gq   = (const float*)d_in[7];
    const float* gk   = (const float*)d_in[8];
    const float* wo   = (const float*)d_in[9];
    const float* awq  = (const float*)d_in[10];
    const float* awk  = (const float*)d_in[11];
    const float* awv  = (const float*)d_in[12];
    const float* agq  = (const float*)d_in[13];
    const float* agk  = (const float*)d_in[14];
    const float* awo  = (const float*)d_in[15];

    unsigned short* wsp = (unsigned short*)d_ws;
    const size_t SZ  = (size_t)SEQ * DIMC;
    const size_t WSZ = (size_t)DIMC * DIMC;
    unsigned short* XC  = wsp;
    unsigned short* Qb  = XC + SZ;
    unsigned short* Kb  = Qb + SZ;
    unsigned short* Vb  = Kb + SZ;
    unsigned short* Vtb = Vb + SZ;
    unsigned short* Ob  = Vtb + SZ;
    unsigned short* Wc  = Ob + SZ;  // 8 weights: awq, wq, awk, wk, awv, wv, awo, wo

    {
        C2 c2a;
        c2a.src[0] = ctx; c2a.n8[0] = (size_t)TXTLEN * DIMC / 8; c2a.dst[0] = XC;
        c2a.src[1] = x;   c2a.n8[1] = (size_t)IMGLEN * DIMC / 8; c2a.dst[1] = XC + (size_t)TXTLEN * DIMC;
        const int maxb = (int)((c2a.n8[1] + 255) / 256);
        castk2<<<dim3(maxb, 2), dim3(256), 0, stream>>>(c2a);
    }
    {
        W8 w8;
        w8.src[0] = awq; w8.src[1] = wq; w8.src[2] = awk; w8.src[3] = wk;
        w8.src[4] = awv; w8.src[5] = wv; w8.src[6] = awo; w8.src[7] = wo;
        const int n8 = (int)(WSZ / 8);
        castw<<<dim3((n8 + 255) / 256, 8), dim3(256), 0, stream>>>(w8, Wc, n8, WSZ);
    }

    QkvArgs qa;
    qa.A = XC;
    qa.w0[0] = Wc + 0 * WSZ; qa.w1[0] = Wc + 1 * WSZ; qa.c[0] = Qb;
    qa.w0[1] = Wc + 2 * WSZ; qa.w1[1] = Wc + 3 * WSZ; qa.c[1] = Kb;
    qa.w0[2] = Wc + 4 * WSZ; qa.w1[2] = Wc + 5 * WSZ; qa.c[2] = Vb;
    gemm_qkv<<<dim3(1440), dim3(256), 0, stream>>>(qa);

    normrope_transpose<<<dim3(NR_BLOCKS + (SEQ / 64) * NHEADS), dim3(256), 0, stream>>>(
        Qb, Kb, gq, gk, agq, agk, rc, rs, Vb, Vtb);

    attn_mfma<<<dim3(480), dim3(512), 0, stream>>>(Qb, Kb, Vtb, Ob);

    float* out = (float*)d_out;
    gemm_out<<<dim3(480), dim3(256), 0, stream>>>(
        Ob, Wc + 6 * WSZ, Wc + 7 * WSZ, out + (size_t)IMGLEN * DIMC, out);
}

// Round 20
// 529.105 us; speedup vs baseline: 1.0144x; 1.0004x over previous
//
#include <hip/hip_runtime.h>
#include <hip/hip_bf16.h>

#define DIMC 3072
#define NHEADS 24
#define HD 128
#define SEQ 2560
#define TXTLEN 512
#define IMGLEN 2048

using short8 = __attribute__((ext_vector_type(8))) short;
using f32x4  = __attribute__((ext_vector_type(4))) float;

static __device__ __forceinline__ float bf2f(unsigned short u) {
    unsigned v = ((unsigned)u) << 16;
    return __builtin_bit_cast(float, v);
}
static __device__ __forceinline__ unsigned short f2bf(float f) {
    unsigned u = __builtin_bit_cast(unsigned, f);
    return (unsigned short)((u + 0x7FFFu + ((u >> 16) & 1u)) >> 16);
}
static __device__ __forceinline__ void gload16(const void* g, void* l) {
    __builtin_amdgcn_global_load_lds((const __attribute__((address_space(1))) unsigned int*)g,
                                     (__attribute__((address_space(3))) unsigned int*)l,
                                     16, 0, 0);
}

// ---------------------------------------------------------------------------
// f32 -> bf16 casts: activations (2 sources, one dispatch) and 8 weights.
// ---------------------------------------------------------------------------
struct C2 { const float* src[2]; size_t n8[2]; unsigned short* dst[2]; };
__global__ __launch_bounds__(256)
void castk2(C2 a)
{
    const int which = blockIdx.y;
    const size_t i = (size_t)blockIdx.x * 256 + threadIdx.x;
    if (i >= a.n8[which]) return;
    const float* in = a.src[which];
    unsigned short* out = a.dst[which];
    const float4 av = *reinterpret_cast<const float4*>(in + i * 8);
    const float4 bv = *reinterpret_cast<const float4*>(in + i * 8 + 4);
    short8 o;
    o[0] = (short)f2bf(av.x); o[1] = (short)f2bf(av.y);
    o[2] = (short)f2bf(av.z); o[3] = (short)f2bf(av.w);
    o[4] = (short)f2bf(bv.x); o[5] = (short)f2bf(bv.y);
    o[6] = (short)f2bf(bv.z); o[7] = (short)f2bf(bv.w);
    *reinterpret_cast<short8*>(out + i * 8) = o;
}

struct W8 { const float* src[8]; };
__global__ __launch_bounds__(256)
void castw(W8 a, unsigned short* __restrict__ dstbase, int n8, size_t wsz)
{
    const int i = blockIdx.x * 256 + threadIdx.x;
    if (i >= n8) return;
    const float* in = a.src[blockIdx.y];
    unsigned short* out = dstbase + (size_t)blockIdx.y * wsz;
    const float4 av = *reinterpret_cast<const float4*>(in + (size_t)i * 8);
    const float4 bv = *reinterpret_cast<const float4*>(in + (size_t)i * 8 + 4);
    short8 o;
    o[0] = (short)f2bf(av.x); o[1] = (short)f2bf(av.y);
    o[2] = (short)f2bf(av.z); o[3] = (short)f2bf(av.w);
    o[4] = (short)f2bf(bv.x); o[5] = (short)f2bf(bv.y);
    o[6] = (short)f2bf(bv.z); o[7] = (short)f2bf(bv.w);
    *reinterpret_cast<short8*>(out + (size_t)i * 8) = o;
}

// ---------------------------------------------------------------------------
// QKV GEMM: 128x128 tile, BK=32, 3-buffer pipeline staged 2 ahead, counted
// vmcnt(4). LDS bank-swizzle: 16B slot ^= (row>>1)&3, on BOTH the
// pre-swizzled global source (linear gload_lds dest) and the ds_read slot.
// XCD-bijective grid swizzle (1440 blocks, chunk 180).
// ---------------------------------------------------------------------------
struct QkvArgs {
    const unsigned short* A;
    const unsigned short* w0[3];
    const unsigned short* w1[3];
    unsigned short* c[3];
};

__global__ __launch_bounds__(256)
void gemm_qkv(QkvArgs args)
{
    __shared__ unsigned short As[3][128 * 32];
    __shared__ unsigned short Bs[3][128 * 32];

    const int bid = blockIdx.x;
    const int swz = (bid & 7) * 180 + (bid >> 3);
    const int bm = swz % 20;
    int bn = swz / 20;                       // 0..71
    const int which = bn / 24; bn -= which * 24;

    const int rowbase = bm * 128, colbase = bn * 128;
    const unsigned short* __restrict__ A = args.A;
    const unsigned short* __restrict__ W = (rowbase < TXTLEN) ? args.w0[which] : args.w1[which];
    unsigned short* __restrict__ C = args.c[which];

    const int t = threadIdx.x, w = t >> 6, l = t & 63;
    const int lr = l & 15, lk = l >> 4;
    const int wr = (w >> 1) * 64, wc = (w & 1) * 64;

    f32x4 acc[4][4] = {};

    const int ssl = ((l & 3) ^ ((l >> 3) & 3)) * 8;   // pre-swizzled source slot
    const unsigned short* Ag = A + (size_t)(rowbase + w * 32 + (l >> 2)) * DIMC + ssl;
    const unsigned short* Wg = W + (size_t)(colbase + w * 32 + (l >> 2)) * DIMC + ssl;

    auto STAGE = [&](int buf, int k0) {
        gload16(Ag + k0,             &As[buf][w * 1024]);
        gload16(Ag + 16 * DIMC + k0, &As[buf][w * 1024 + 512]);
        gload16(Wg + k0,             &Bs[buf][w * 1024]);
        gload16(Wg + 16 * DIMC + k0, &Bs[buf][w * 1024 + 512]);
    };

    constexpr int NIT = DIMC / 32;   // 96
    STAGE(0, 0);
    STAGE(1, 32);

    const int rsl = (lk ^ ((lr >> 1) & 3)) * 8;   // swizzled ds_read slot
    int buf = 0;
    for (int it = 0; it < NIT; ++it) {
        asm volatile("s_waitcnt vmcnt(4)" ::: "memory");
        __builtin_amdgcn_s_barrier();
        asm volatile("" ::: "memory");

        {
            const int k2 = (it + 2 < NIT) ? (it + 2) : (NIT - 1);
            int b2 = buf + 2; if (b2 >= 3) b2 -= 3;
            STAGE(b2, k2 * 32);
        }

        short8 af[4], bf[4];
#pragma unroll
        for (int m = 0; m < 4; ++m)
            af[m] = *reinterpret_cast<const short8*>(&As[buf][(wr + m * 16 + lr) * 32 + rsl]);
#pragma unroll
        for (int n = 0; n < 4; ++n)
            bf[n] = *reinterpret_cast<const short8*>(&Bs[buf][(wc + n * 16 + lr) * 32 + rsl]);

        __builtin_amdgcn_s_setprio(1);
#pragma unroll
        for (int m = 0; m < 4; ++m)
#pragma unroll
            for (int n = 0; n < 4; ++n)
                acc[m][n] = __builtin_amdgcn_mfma_f32_16x16x32_bf16(af[m], bf[n], acc[m][n], 0, 0, 0);
        __builtin_amdgcn_s_setprio(0);

        buf = (buf + 1 == 3) ? 0 : buf + 1;
    }

#pragma unroll
    for (int m = 0; m < 4; ++m) {
#pragma unroll
        for (int r = 0; r < 4; ++r) {
            const int row = rowbase + wr + m * 16 + lk * 4 + r;
            unsigned short* crow = C + (size_t)row * DIMC + colbase + wc;
#pragma unroll
            for (int n = 0; n < 4; ++n)
                crow[n * 16 + lr] = f2bf(acc[m][n][r]);
        }
    }
}

// ---------------------------------------------------------------------------
// Output projection GEMM (f32 out, txt/img split), same pipeline + swizzle.
// ---------------------------------------------------------------------------
__global__ __launch_bounds__(256)
void gemm_out(const unsigned short* __restrict__ A, const unsigned short* __restrict__ W0,
              const unsigned short* __restrict__ W1, float* __restrict__ Ctxt,
              float* __restrict__ Cimg)
{
    __shared__ unsigned short As[3][128 * 32];
    __shared__ unsigned short Bs[3][128 * 32];

    const int bid = blockIdx.x;
    const int swz = (bid & 7) * 60 + (bid >> 3);
    const int bm = swz % 20;
    const int bn = swz / 20;                  // 0..23

    const int rowbase = bm * 128, colbase = bn * 128;
    const unsigned short* __restrict__ W = (rowbase < TXTLEN) ? W0 : W1;

    const int t = threadIdx.x, w = t >> 6, l = t & 63;
    const int lr = l & 15, lk = l >> 4;
    const int wr = (w >> 1) * 64, wc = (w & 1) * 64;

    f32x4 acc[4][4] = {};

    const int ssl = ((l & 3) ^ ((l >> 3) & 3)) * 8;
    const unsigned short* Ag = A + (size_t)(rowbase + w * 32 + (l >> 2)) * DIMC + ssl;
    const unsigned short* Wg = W + (size_t)(colbase + w * 32 + (l >> 2)) * DIMC + ssl;

    auto STAGE = [&](int buf, int k0) {
        gload16(Ag + k0,             &As[buf][w * 1024]);
        gload16(Ag + 16 * DIMC + k0, &As[buf][w * 1024 + 512]);
        gload16(Wg + k0,             &Bs[buf][w * 1024]);
        gload16(Wg + 16 * DIMC + k0, &Bs[buf][w * 1024 + 512]);
    };

    constexpr int NIT = DIMC / 32;
    STAGE(0, 0);
    STAGE(1, 32);

    const int rsl = (lk ^ ((lr >> 1) & 3)) * 8;
    int buf = 0;
    for (int it = 0; it < NIT; ++it) {
        asm volatile("s_waitcnt vmcnt(4)" ::: "memory");
        __builtin_amdgcn_s_barrier();
        asm volatile("" ::: "memory");

        {
            const int k2 = (it + 2 < NIT) ? (it + 2) : (NIT - 1);
            int b2 = buf + 2; if (b2 >= 3) b2 -= 3;
            STAGE(b2, k2 * 32);
        }

        short8 af[4], bf[4];
#pragma unroll
        for (int m = 0; m < 4; ++m)
            af[m] = *reinterpret_cast<const short8*>(&As[buf][(wr + m * 16 + lr) * 32 + rsl]);
#pragma unroll
        for (int n = 0; n < 4; ++n)
            bf[n] = *reinterpret_cast<const short8*>(&Bs[buf][(wc + n * 16 + lr) * 32 + rsl]);

        __builtin_amdgcn_s_setprio(1);
#pragma unroll
        for (int m = 0; m < 4; ++m)
#pragma unroll
            for (int n = 0; n < 4; ++n)
                acc[m][n] = __builtin_amdgcn_mfma_f32_16x16x32_bf16(af[m], bf[n], acc[m][n], 0, 0, 0);
        __builtin_amdgcn_s_setprio(0);

        buf = (buf + 1 == 3) ? 0 : buf + 1;
    }

    float* Cb; int rloc;
    if (rowbase < TXTLEN) { Cb = Ctxt; rloc = rowbase; }
    else                  { Cb = Cimg; rloc = rowbase - TXTLEN; }
#pragma unroll
    for (int m = 0; m < 4; ++m) {
#pragma unroll
        for (int r = 0; r < 4; ++r) {
            const int row = rloc + wr + m * 16 + lk * 4 + r;
            float* crow = Cb + (size_t)row * DIMC + colbase + wc;
#pragma unroll
            for (int n = 0; n < 4; ++n)
                crow[n * 16 + lr] = acc[m][n][r];
        }
    }
}

// ---------------------------------------------------------------------------
// Fused normrope + transpose_v: one dispatch, blockIdx-partitioned.
// bid < 15360: RMSNorm+RoPE on Q,K (one wave per (s,h) row).
// bid >= 15360: V[2560][3072] -> Vt[24][128][2560] tile transpose.
// The two paths touch disjoint buffers; merging removes one launch/drain.
// ---------------------------------------------------------------------------
#define NR_BLOCKS (SEQ * NHEADS / 4)   // 15360

__global__ __launch_bounds__(256)
void normrope_transpose(unsigned short* __restrict__ Q, unsigned short* __restrict__ K,
                        const float* __restrict__ gq, const float* __restrict__ gk,
                        const float* __restrict__ agq, const float* __restrict__ agk,
                        const float* __restrict__ rc, const float* __restrict__ rs,
                        const unsigned short* __restrict__ V, unsigned short* __restrict__ Vt)
{
    __shared__ unsigned short Ts[64][136];
    const int bid = blockIdx.x;

    if (bid < NR_BLOCKS) {
        // ---- normrope path ----
        const int wid  = (bid << 2) + (threadIdx.x >> 6);
        const int lane = threadIdx.x & 63;
        const int s = wid / NHEADS, h = wid - s * NHEADS;
        const bool img = (s >= TXTLEN);
        const float* gq_ = img ? gq : agq;
        const float* gk_ = img ? gk : agk;

        const size_t base = (size_t)s * DIMC + h * HD + lane * 2;
        const float2 c2  = *reinterpret_cast<const float2*>(rc + (size_t)s * HD + lane * 2);
        const float2 s2  = *reinterpret_cast<const float2*>(rs + (size_t)s * HD + lane * 2);
        const float2 gqv = *reinterpret_cast<const float2*>(gq_ + lane * 2);
        const float2 gkv = *reinterpret_cast<const float2*>(gk_ + lane * 2);

        {
            unsigned pr = *reinterpret_cast<unsigned*>(Q + base);
            float vx = bf2f((unsigned short)(pr & 0xffff));
            float vy = bf2f((unsigned short)(pr >> 16));
            float ss = vx * vx + vy * vy;
#pragma unroll
            for (int off = 1; off < 64; off <<= 1) ss += __shfl_xor(ss, off);
            const float rr = rsqrtf(ss * (1.f / HD) + 1e-6f);
            const float txv = vx * rr * gqv.x, tyv = vy * rr * gqv.y;
            const float qs = 0.08838834764831845f;
            const float ox = (txv * c2.x - tyv * s2.x) * qs;
            const float oy = (tyv * c2.y + txv * s2.y) * qs;
            *reinterpret_cast<unsigned*>(Q + base) = (unsigned)f2bf(ox) | ((unsigned)f2bf(oy) << 16);
        }
        {
            unsigned pr = *reinterpret_cast<unsigned*>(K + base);
            float vx = bf2f((unsigned short)(pr & 0xffff));
            float vy = bf2f((unsigned short)(pr >> 16));
            float ss = vx * vx + vy * vy;
#pragma unroll
            for (int off = 1; off < 64; off <<= 1) ss += __shfl_xor(ss, off);
            const float rr = rsqrtf(ss * (1.f / HD) + 1e-6f);
            const float txv = vx * rr * gkv.x, tyv = vy * rr * gkv.y;
            const float ox = txv * c2.x - tyv * s2.x;
            const float oy = tyv * c2.y + txv * s2.y;
            *reinterpret_cast<unsigned*>(K + base) = (unsigned)f2bf(ox) | ((unsigned)f2bf(oy) << 16);
        }
    } else {
        // ---- transpose_v path ----
        const int b2 = bid - NR_BLOCKS;
        const int kt = b2 % (SEQ / 64);
        const int h  = b2 / (SEQ / 64);
        const int t = threadIdx.x;
#pragma unroll
        for (int p = 0; p < 4; ++p) {
            const int row = p * 16 + (t >> 4);
            const int col = (t & 15) * 8;
            *reinterpret_cast<short8*>(&Ts[row][col]) =
                *reinterpret_cast<const short8*>(V + (size_t)(kt * 64 + row) * DIMC + h * HD + col);
        }
        __syncthreads();
        const int d = t >> 1, kh = t & 1;
        unsigned short* dst = Vt + (size_t)h * HD * SEQ + (size_t)d * SEQ + kt * 64 + kh * 32;
#pragma unroll
        for (int j4 = 0; j4 < 4; ++j4) {
            short8 o;
#pragma unroll
            for (int j = 0; j < 8; ++j) o[j] = (short)Ts[kh * 32 + j4 * 8 + j][d];
            *reinterpret_cast<short8*>(dst + j4 * 8) = o;
        }
    }
}

// ---------------------------------------------------------------------------
// Flash attention: 128 q-rows x 1 head per block, 8 waves, XCD-swizzled grid.
// K/V double-buffered (XOR-swizzled via pre-swizzled global src).
// T5 setprio + T13 defer-max.
// ---------------------------------------------------------------------------
__global__ __launch_bounds__(512)
void attn_mfma(const unsigned short* __restrict__ Q, const unsigned short* __restrict__ K,
               const unsigned short* __restrict__ Vt, unsigned short* __restrict__ O)
{
    __shared__ unsigned short Ks[2][64 * 128];   // [kv][d], slot^=(kv&7)
    __shared__ unsigned short Vs[2][128 * 64];   // [d][kv], slot^=(d&7)
    __shared__ unsigned short Ps[8][16 * 64];    // per-wave P, swizzled

    const int bid = blockIdx.x;
    const int swz = (bid & 7) * 60 + (bid >> 3);
    const int bq = swz % 20;
    const int h  = swz / 20;

    const int t = threadIdx.x, w = t >> 6, l = t & 63;
    const int lr = l & 15, lk = l >> 4;
    const int q0 = bq * 128 + w * 16;

    short8 qf[4];
#pragma unroll
    for (int kk = 0; kk < 4; ++kk)
        qf[kk] = *reinterpret_cast<const short8*>(
            Q + (size_t)(q0 + lr) * DIMC + h * HD + kk * 32 + lk * 8);

    f32x4 oacc[8] = {};
    float mrow[4] = {-1e30f, -1e30f, -1e30f, -1e30f};
    float lrow[4] = {};

    const unsigned short* Kg[2];
    const unsigned short* Vg[2];
#pragma unroll
    for (int i = 0; i < 2; ++i) {
        const int kr = w * 8 + i * 4 + (l >> 4);
        Kg[i] = K + (size_t)kr * DIMC + h * HD + (((l & 15) ^ (kr & 7)) * 8);
        const int vr = w * 16 + i * 8 + (l >> 3);
        Vg[i] = Vt + (size_t)h * HD * SEQ + (size_t)vr * SEQ + (((l & 7) ^ (vr & 7)) * 8);
    }

    auto STAGE = [&](int buf, int kv0) {
#pragma unroll
        for (int i = 0; i < 2; ++i) {
            gload16(Kg[i] + (size_t)kv0 * DIMC, &Ks[buf][(w * 8 + i * 4) * 128]);
            gload16(Vg[i] + kv0,                &Vs[buf][(w * 16 + i * 8) * 64]);
        }
    };

    STAGE(0, 0);

    constexpr int NT = SEQ / 64;  // 40
    for (int kt = 0; kt < NT; ++kt) {
        const int buf = kt & 1;
        __syncthreads();
        if (kt + 1 < NT) STAGE(buf ^ 1, (kt + 1) * 64);

        // S = Q K^T
        f32x4 sf[4] = {};
        __builtin_amdgcn_s_setprio(1);
#pragma unroll
        for (int nf = 0; nf < 4; ++nf) {
            const int row = nf * 16 + lr;
            const int sw = (row & 7) << 3;
#pragma unroll
            for (int kk = 0; kk < 4; ++kk) {
                short8 bfr = *reinterpret_cast<const short8*>(
                    &Ks[buf][row * 128 + ((kk * 32 + lk * 8) ^ sw)]);
                sf[nf] = __builtin_amdgcn_mfma_f32_16x16x32_bf16(qf[kk], bfr, sf[nf], 0, 0, 0);
            }
        }
        __builtin_amdgcn_s_setprio(0);

        // online softmax with defer-max (T13)
        float mxr[4];
#pragma unroll
        for (int r = 0; r < 4; ++r) {
            float mx = fmaxf(fmaxf(sf[0][r], sf[1][r]), fmaxf(sf[2][r], sf[3][r]));
#pragma unroll
            for (int off = 1; off < 16; off <<= 1) mx = fmaxf(mx, __shfl_xor(mx, off));
            mxr[r] = mx;
        }
        const float need = fmaxf(fmaxf(mxr[0] - mrow[0], mxr[1] - mrow[1]),
                                 fmaxf(mxr[2] - mrow[2], mxr[3] - mrow[3]));
        if (!__all(need <= 8.0f)) {
#pragma unroll
            for (int r = 0; r < 4; ++r) {
                const float mn = fmaxf(mrow[r], mxr[r]);
                const float alpha = __expf(mrow[r] - mn);
                mrow[r] = mn;
                lrow[r] *= alpha;
#pragma unroll
                for (int nf = 0; nf < 8; ++nf) oacc[nf][r] *= alpha;
            }
        }
#pragma unroll
        for (int r = 0; r < 4; ++r) {
            float ps = 0.f;
#pragma unroll
            for (int nf = 0; nf < 4; ++nf) {
                const float p = __expf(sf[nf][r] - mrow[r]);
                sf[nf][r] = p;
                ps += p;
            }
#pragma unroll
            for (int off = 1; off < 16; off <<= 1) ps += __shfl_xor(ps, off);
            lrow[r] += ps;
        }

        // P -> per-wave LDS (swizzled); same-wave producer/consumer
#pragma unroll
        for (int r = 0; r < 4; ++r) {
            const int prow = lk * 4 + r;
            const int sw = (prow & 7) << 3;
#pragma unroll
            for (int nf = 0; nf < 4; ++nf) {
                const int col = nf * 16 + lr;
                Ps[w][prow * 64 + (col ^ sw)] = f2bf(sf[nf][r]);
            }
        }

        // O += P V
        __builtin_amdgcn_s_setprio(1);
#pragma unroll
        for (int ks = 0; ks < 2; ++ks) {
            short8 pa = *reinterpret_cast<const short8*>(
                &Ps[w][lr * 64 + ((ks * 32 + lk * 8) ^ ((lr & 7) << 3))]);
#pragma unroll
            for (int nf = 0; nf < 8; ++nf) {
                const int vrow = nf * 16 + lr;
                short8 vf = *reinterpret_cast<const short8*>(
                    &Vs[buf][vrow * 64 + ((ks * 32 + lk * 8) ^ ((vrow & 7) << 3))]);
                oacc[nf] = __builtin_amdgcn_mfma_f32_16x16x32_bf16(pa, vf, oacc[nf], 0, 0, 0);
            }
        }
        __builtin_amdgcn_s_setprio(0);
    }

    float inv[4];
#pragma unroll
    for (int r = 0; r < 4; ++r) inv[r] = 1.f / lrow[r];
#pragma unroll
    for (int nf = 0; nf < 8; ++nf)
#pragma unroll
        for (int r = 0; r < 4; ++r)
            O[(size_t)(q0 + lk * 4 + r) * DIMC + h * HD + nf * 16 + lr] = f2bf(oacc[nf][r] * inv[r]);
}

// ---------------------------------------------------------------------------
extern "C" void kernel_launch(void* const* d_in, const int* in_sizes, int n_in,
                              void* d_out, int out_size, void* d_ws, size_t ws_size,
                              hipStream_t stream)
{
    const float* x    = (const float*)d_in[0];
    const float* ctx  = (const float*)d_in[1];
    const float* rc   = (const float*)d_in[2];
    const float* rs   = (const float*)d_in[3];
    const float* wq   = (const float*)d_in[4];
    const float* wk   = (const float*)d_in[5];
    const float* wv   = (const float*)d_in[6];
    const float* gq   = (const float*)d_in[7];
    const float* gk   = (const float*)d_in[8];
    const float* wo   = (const float*)d_in[9];
    const float* awq  = (const float*)d_in[10];
    const float* awk  = (const float*)d_in[11];
    const float* awv  = (const float*)d_in[12];
    const float* agq  = (const float*)d_in[13];
    const float* agk  = (const float*)d_in[14];
    const float* awo  = (const float*)d_in[15];

    unsigned short* wsp = (unsigned short*)d_ws;
    const size_t SZ  = (size_t)SEQ * DIMC;
    const size_t WSZ = (size_t)DIMC * DIMC;
    unsigned short* XC  = wsp;
    unsigned short* Qb  = XC + SZ;
    unsigned short* Kb  = Qb + SZ;
    unsigned short* Vb  = Kb + SZ;
    unsigned short* Vtb = Vb + SZ;
    unsigned short* Ob  = Vtb + SZ;
    unsigned short* Wc  = Ob + SZ;  // 8 weights: awq, wq, awk, wk, awv, wv, awo, wo

    {
        C2 c2a;
        c2a.src[0] = ctx; c2a.n8[0] = (size_t)TXTLEN * DIMC / 8; c2a.dst[0] = XC;
        c2a.src[1] = x;   c2a.n8[1] = (size_t)IMGLEN * DIMC / 8; c2a.dst[1] = XC + (size_t)TXTLEN * DIMC;
        const int maxb = (int)((c2a.n8[1] + 255) / 256);
        castk2<<<dim3(maxb, 2), dim3(256), 0, stream>>>(c2a);
    }
    {
        W8 w8;
        w8.src[0] = awq; w8.src[1] = wq; w8.src[2] = awk; w8.src[3] = wk;
        w8.src[4] = awv; w8.src[5] = wv; w8.src[6] = awo; w8.src[7] = wo;
        const int n8 = (int)(WSZ / 8);
        castw<<<dim3((n8 + 255) / 256, 8), dim3(256), 0, stream>>>(w8, Wc, n8, WSZ);
    }

    QkvArgs qa;
    qa.A = XC;
    qa.w0[0] = Wc + 0 * WSZ; qa.w1[0] = Wc + 1 * WSZ; qa.c[0] = Qb;
    qa.w0[1] = Wc + 2 * WSZ; qa.w1[1] = Wc + 3 * WSZ; qa.c[1] = Kb;
    qa.w0[2] = Wc + 4 * WSZ; qa.w1[2] = Wc + 5 * WSZ; qa.c[2] = Vb;
    gemm_qkv<<<dim3(1440), dim3(256), 0, stream>>>(qa);

    normrope_transpose<<<dim3(NR_BLOCKS + (SEQ / 64) * NHEADS), dim3(256), 0, stream>>>(
        Qb, Kb, gq, gk, agq, agk, rc, rs, Vb, Vtb);

    attn_mfma<<<dim3(480), dim3(512), 0, stream>>>(Qb, Kb, Vtb, Ob);

    float* out = (float*)d_out;
    gemm_out<<<dim3(480), dim3(256), 0, stream>>>(
        Ob, Wc + 6 * WSZ, Wc + 7 * WSZ, out + (size_t)IMGLEN * DIMC, out);
}